// Round 13
// baseline (93.552 us; speedup 1.0000x reference)
//
#include <hip/hip_runtime.h>
#include <math.h>

#define KMAX 8
#define CSTRIDE 64   // ints between expert counters = 256 B -> distinct cache lines

typedef short s16x8 __attribute__((ext_vector_type(8)));
typedef float f32x4 __attribute__((ext_vector_type(4)));

__device__ inline ushort f2bf(float f) {
    union { float f; unsigned u; } v; v.f = f;
    unsigned r = v.u + 0x7fffu + ((v.u >> 16) & 1u);   // RNE
    return (ushort)(r >> 16);
}
__device__ inline float bf2f(ushort b) {
    union { unsigned u; float f; } v; v.u = ((unsigned)b) << 16; return v.f;
}

__device__ inline void gload_lds16(const void* g, void* l) {
    __builtin_amdgcn_global_load_lds(
        (const __attribute__((address_space(1))) unsigned int*)g,
        (__attribute__((address_space(3))) unsigned int*)l, 16, 0, 0);
}

// ---------------------------------------------------------------------------
// K_fused: blocks [0, nSB) = scores+top-k+scatter (+x->bf16 mirror, +local
// ef-norms); blocks [nSB, nSB+E*bpe) = UNGATED W->bf16 conversion.
// The W-conv blocks have no dependency on the scores blocks (and vice versa)
// so they overlap the latency-bound scores phase — replaces the separate,
// counts-gated k_prep_w that serialized behind scores.
// ef norms are computed PER-BLOCK from the already-staged ef tiles (f32 chain
// per 64-chunk + f64 accum — same error class as the dots, proven rounds
// 2-12), removing the k_efnorm kernel and the efn buffer dependency.
// ---------------------------------------------------------------------------
__global__ __launch_bounds__(256) void k_fused(
    const float* __restrict__ x, const float* __restrict__ ef,
    const float* __restrict__ trust, const float* __restrict__ stale,
    const float* __restrict__ W, const int* __restrict__ kp,
    int D, int B, int C, int nSB, int bpe,
    ushort* __restrict__ xbf, ushort* __restrict__ wbf,
    int* __restrict__ counts, int* __restrict__ lists, int* __restrict__ sel)
{
    __shared__ float xs[16 * 64];           // 4 KB
    __shared__ float efs[32 * 64];          // 8 KB
    __shared__ double sc[16 * 33];
    __shared__ int bcnt[32];
    __shared__ int bbase[32];
    __shared__ unsigned char selb[16 * KMAX];
    __shared__ unsigned char lposb[16 * KMAX];

    int tid = threadIdx.x;

    // ---------------- W-conversion blocks (ungated, overlap scores) --------
    if ((int)blockIdx.x >= nSB) {
        int wb = blockIdx.x - nSB;
        int e = wb / bpe, sub = wb % bpe;
        int perExpF4 = (C * D) / 4;
        size_t base = (size_t)e * perExpF4;
        #pragma unroll
        for (int j = 0; j < 4; ++j) {
            int idx = (sub * 4 + j) * 256 + tid;
            if (idx < perExpF4) {
                float4 v = *(const float4*)&W[(base + idx) * 4];
                ushort4 u;
                u.x = f2bf(v.x); u.y = f2bf(v.y);
                u.z = f2bf(v.z); u.w = f2bf(v.w);
                *(ushort4*)&wbf[(base + idx) * 4] = u;
            }
        }
        return;
    }

    // ---------------- scores blocks (round-12 proven structure) ------------
    int tp = tid >> 4, eg = tid & 15;
    int tb = blockIdx.x * 16;

    if (tid < 32) bcnt[tid] = 0;

    int rx = tid >> 4, qx = tid & 15;
    int re0 = tid >> 4, re1 = 16 + (tid >> 4);
    int qe = tid & 15;

    int nch = D / 64;

    float4 vx  = *(const float4*)&x[(size_t)(tb + rx) * D + qx * 4];
    float4 ve0 = *(const float4*)&ef[(size_t)re0 * D + qe * 4];
    float4 ve1 = *(const float4*)&ef[(size_t)re1 * D + qe * 4];

    double acc0 = 0.0, acc1 = 0.0, axx = 0.0;
    double nacc0 = 0.0, nacc1 = 0.0;        // ef-norm accumulators (local efn)

    for (int ch = 0; ch < nch; ++ch) {
        *(float4*)&xs[rx * 64 + ((qx ^ rx) << 2)] = vx;
        {
            ushort4 u;
            u.x = f2bf(vx.x); u.y = f2bf(vx.y); u.z = f2bf(vx.z); u.w = f2bf(vx.w);
            *(ushort4*)&xbf[(size_t)(tb + rx) * D + ch * 64 + qx * 4] = u;
        }
        *(float4*)&efs[re0 * 64 + ((qe ^ (re0 & 15)) << 2)] = ve0;
        *(float4*)&efs[re1 * 64 + ((qe ^ (re1 & 15)) << 2)] = ve1;
        __syncthreads();

        // T14: issue NEXT chunk's loads before compute
        if (ch + 1 < nch) {
            int k1 = (ch + 1) * 64;
            vx  = *(const float4*)&x[(size_t)(tb + rx) * D + k1 + qx * 4];
            ve0 = *(const float4*)&ef[(size_t)re0 * D + k1 + qe * 4];
            ve1 = *(const float4*)&ef[(size_t)re1 * D + k1 + qe * 4];
        }

        float a0 = 0.f, a1 = 0.f, ax = 0.f, n0 = 0.f, n1 = 0.f;
        #pragma unroll
        for (int q = 0; q < 16; ++q) {
            float4 xv = *(const float4*)&xs[tp * 64 + ((q ^ tp) << 2)];
            float4 e0 = *(const float4*)&efs[eg * 64 + ((q ^ eg) << 2)];
            float4 e1 = *(const float4*)&efs[(eg + 16) * 64 + ((q ^ eg) << 2)];
            a0 = fmaf(xv.x, e0.x, a0); a0 = fmaf(xv.y, e0.y, a0);
            a0 = fmaf(xv.z, e0.z, a0); a0 = fmaf(xv.w, e0.w, a0);
            a1 = fmaf(xv.x, e1.x, a1); a1 = fmaf(xv.y, e1.y, a1);
            a1 = fmaf(xv.z, e1.z, a1); a1 = fmaf(xv.w, e1.w, a1);
            ax = fmaf(xv.x, xv.x, ax); ax = fmaf(xv.y, xv.y, ax);
            ax = fmaf(xv.z, xv.z, ax); ax = fmaf(xv.w, xv.w, ax);
            n0 = fmaf(e0.x, e0.x, n0); n0 = fmaf(e0.y, e0.y, n0);
            n0 = fmaf(e0.z, e0.z, n0); n0 = fmaf(e0.w, e0.w, n0);
            n1 = fmaf(e1.x, e1.x, n1); n1 = fmaf(e1.y, e1.y, n1);
            n1 = fmaf(e1.z, e1.z, n1); n1 = fmaf(e1.w, e1.w, n1);
        }
        __syncthreads();
        acc0 += (double)a0; acc1 += (double)a1; axx += (double)ax;
        nacc0 += (double)n0; nacc1 += (double)n1;
    }

    double xn = fmax(sqrt(axx), 1e-8);
    {
        int e0i = eg;
        double en0 = fmax(sqrt(nacc0), 1e-8);
        sc[tp * 33 + e0i] = 0.4 * (double)trust[e0i]
            + 0.2 * (acc0 / (xn * en0) + 1.0)
            + 0.2 * fmax(0.0, 1.0 - (double)stale[e0i]);
        int e1i = eg + 16;
        double en1 = fmax(sqrt(nacc1), 1e-8);
        sc[tp * 33 + e1i] = 0.4 * (double)trust[e1i]
            + 0.2 * (acc1 / (xn * en1) + 1.0)
            + 0.2 * fmax(0.0, 1.0 - (double)stale[e1i]);
    }
    __syncthreads();

    int kk = kp[0]; kk = kk < 1 ? 1 : (kk > KMAX ? KMAX : kk);

    // per-token top-k (strict > scan, lowest-index tie-break == jax.lax.top_k
    // selected set); hierarchical scatter (round-4 fix)
    if (tid < 16) {
        unsigned mask = 0;
        for (int p = 0; p < kk; ++p) {
            double bv = -1e300; int be = 0;
            #pragma unroll
            for (int e = 0; e < 32; ++e) {
                double v = sc[tid * 33 + e];
                if (!((mask >> e) & 1u) && v > bv) { bv = v; be = e; }
            }
            mask |= 1u << be;
            selb[tid * KMAX + p] = (unsigned char)be;
            lposb[tid * KMAX + p] = (unsigned char)atomicAdd(&bcnt[be], 1);
        }
    }
    __syncthreads();
    if (tid < 32) {
        int c = bcnt[tid];
        bbase[tid] = c ? atomicAdd(&counts[tid * CSTRIDE], c) : 0;
    }
    __syncthreads();
    if (tid < 16) {
        int t = tb + tid;
        for (int p = 0; p < kk; ++p) {
            int e = selb[tid * KMAX + p];
            int pos = bbase[e] + lposb[tid * KMAX + p];
            lists[(size_t)e * B + pos] = t;
            sel[(size_t)t * KMAX + p] = (e << 24) | pos;
        }
    }
}

// ---------------------------------------------------------------------------
// K4 v3: grouped expert GEMM (round-10 proven — BM=128, BN=128, 512 threads
// = 8 waves, wave tile 32x64, single-buffer 2-barrier K-loop, XOR swizzle
// both sides -> 0 conflicts, bf16 part stores / atomic fallback).
// offs[e] prefix-scan now computed inline (32 uniform L2 loads, scalar).
// ---------------------------------------------------------------------------
__global__ __launch_bounds__(512) void k_moe3(
    const ushort* __restrict__ xbf, const ushort* __restrict__ wbf,
    const float* __restrict__ bias, const int* __restrict__ lists,
    const int* __restrict__ counts, const int* __restrict__ kp,
    int B, int C, int D, int usePart,
    ushort* __restrict__ part, float* __restrict__ out)
{
    int e = blockIdx.z;
    int cnt = counts[e * CSTRIDE];
    int row0 = blockIdx.x * 128;
    if (row0 >= cnt) return;            // uniform: safe before barriers
    int col0 = blockIdx.y * 128;
    int nt = min(128, cnt - row0);

    __shared__ ushort xs[128 * 64];     // 16 KB
    __shared__ ushort wsh[128 * 64];    // 16 KB
    __shared__ int toks[128];

    int tid = threadIdx.x;
    if (tid < 128) toks[tid] = (tid < nt) ? lists[(size_t)e * B + row0 + tid] : 0;
    __syncthreads();

    int lane = tid & 63, wid = tid >> 6;
    int wr = wid >> 1, wc = wid & 1;    // wave tile: rows wr*32, cols wc*64
    int l15 = lane & 15, l16 = lane >> 4;

    f32x4 acc[2][4];
    #pragma unroll
    for (int m = 0; m < 2; ++m)
        #pragma unroll
        for (int n = 0; n < 4; ++n) acc[m][n] = (f32x4){0.f, 0.f, 0.f, 0.f};

    int nch = D / 64;
    for (int ch = 0; ch < nch; ++ch) {
        int k0 = ch * 64;
        #pragma unroll
        for (int t = 0; t < 2; ++t) {
            int id = t * 512 + tid;
            int r = id >> 3, seg = id & 7;
            int ssw = (seg ^ (r & 7)) << 3;
            gload_lds16(&xbf[(size_t)toks[r] * D + k0 + ssw],
                        (char*)xs + (size_t)(t * 512 + wid * 64) * 16);
        }
        #pragma unroll
        for (int t = 0; t < 2; ++t) {
            int id = t * 512 + tid;
            int r = id >> 3, seg = id & 7;
            int ssw = (seg ^ (r & 7)) << 3;
            gload_lds16(&wbf[((size_t)e * C + col0 + r) * D + k0 + ssw],
                        (char*)wsh + (size_t)(t * 512 + wid * 64) * 16);
        }
        __syncthreads();
        #pragma unroll
        for (int ks = 0; ks < 2; ++ks) {
            s16x8 a[2], bfr[4];
            int sbase = ks * 4 + l16;
            #pragma unroll
            for (int m = 0; m < 2; ++m) {
                int r = wr * 32 + m * 16 + l15;
                a[m] = *(const s16x8*)&xs[r * 64 + ((sbase ^ (l15 & 7)) << 3)];
            }
            #pragma unroll
            for (int n = 0; n < 4; ++n) {
                int r = wc * 64 + n * 16 + l15;
                bfr[n] = *(const s16x8*)&wsh[r * 64 + ((sbase ^ (l15 & 7)) << 3)];
            }
            #pragma unroll
            for (int m = 0; m < 2; ++m)
                #pragma unroll
                for (int n = 0; n < 4; ++n)
                    acc[m][n] = __builtin_amdgcn_mfma_f32_16x16x32_bf16(
                        a[m], bfr[n], acc[m][n], 0, 0, 0);
        }
        __syncthreads();
    }

    int kk = kp[0]; kk = kk < 1 ? 1 : (kk > KMAX ? KMAX : kk);
    // C/D layout (m89): col = lane&15, row = (lane>>4)*4 + reg
    if (usePart) {
        int offE = 0;
        for (int e2 = 0; e2 < e; ++e2) offE += counts[e2 * CSTRIDE];
        int slotBase = offE + row0;
        #pragma unroll
        for (int m = 0; m < 2; ++m) {
            int rbase = wr * 32 + m * 16 + l16 * 4;
            #pragma unroll
            for (int n = 0; n < 4; ++n) {
                int col = col0 + wc * 64 + n * 16 + l15;
                float bv = bias[(size_t)e * C + col];
                #pragma unroll
                for (int r = 0; r < 4; ++r) {
                    int rl = rbase + r;
                    if (rl < nt)
                        part[(size_t)(slotBase + rl) * C + col] =
                            f2bf(acc[m][n][r] + bv);
                }
            }
        }
    } else {
        float invk = 1.0f / (float)kk;
        #pragma unroll
        for (int m = 0; m < 2; ++m) {
            int rbase = wr * 32 + m * 16 + l16 * 4;
            #pragma unroll
            for (int n = 0; n < 4; ++n) {
                int col = col0 + wc * 64 + n * 16 + l15;
                float bv = bias[(size_t)e * C + col];
                #pragma unroll
                for (int r = 0; r < 4; ++r) {
                    int rl = rbase + r;
                    if (rl < nt)
                        atomicAdd(&out[(size_t)toks[rl] * C + col],
                                  invk * (acc[m][n][r] + bv));
                }
            }
        }
    }
}

// ---------------------------------------------------------------------------
// K5: combine — out[t][c] = (1/k) * sum_p bf2f(part[slot_p*C + c]).
// offs computed inline from counts (wave-uniform scalar loops, L2-hot).
// ---------------------------------------------------------------------------
__global__ __launch_bounds__(256) void k_combine(
    const ushort* __restrict__ part, const int* __restrict__ sel,
    const int* __restrict__ counts, const int* __restrict__ kp,
    int C, float* __restrict__ out)
{
    int kk = kp[0]; kk = kk < 1 ? 1 : (kk > KMAX ? KMAX : kk);
    float invk = 1.0f / (float)kk;
    int sub = threadIdx.x >> 6, lane = threadIdx.x & 63;
    int t = blockIdx.x * 4 + sub;
    int slot[KMAX];
    for (int p = 0; p < kk; ++p) {
        int sv = sel[(size_t)t * KMAX + p];
        int e = sv >> 24;
        int offE = 0;
        for (int e2 = 0; e2 < e; ++e2) offE += counts[e2 * CSTRIDE];
        slot[p] = offE + (sv & 0xFFFFFF);
    }
    for (int c = lane * 4; c < C; c += 256) {
        float s0 = 0.f, s1 = 0.f, s2 = 0.f, s3 = 0.f;
        for (int p = 0; p < kk; ++p) {
            ushort4 u = *(const ushort4*)&part[(size_t)slot[p] * C + c];
            s0 += bf2f(u.x); s1 += bf2f(u.y); s2 += bf2f(u.z); s3 += bf2f(u.w);
        }
        float4 o = make_float4(invk * s0, invk * s1, invk * s2, invk * s3);
        *(float4*)&out[(size_t)t * C + c] = o;
    }
}

// ===========================================================================
// Legacy fallback — only if ws_size is too small for the bf16 mirrors.
// ===========================================================================
__global__ void k_efnorm(const float* __restrict__ ef, int D,
                         double* __restrict__ efn) {
    int e = blockIdx.x;
    int lane = threadIdx.x;  // 64
    double s = 0.0;
    for (int i = lane; i < D; i += 64) {
        double v = (double)ef[(size_t)e * D + i];
        s = fma(v, v, s);
    }
    #pragma unroll
    for (int off = 32; off > 0; off >>= 1) s += __shfl_xor(s, off);
    if (lane == 0) efn[e] = sqrt(s);
}

__global__ __launch_bounds__(256) void k_scores_legacy(
    const float* __restrict__ x, const float* __restrict__ ef,
    const float* __restrict__ trust, const float* __restrict__ stale,
    const double* __restrict__ efn, const int* __restrict__ kp,
    int D, int B, int* __restrict__ counts, int* __restrict__ lists)
{
    __shared__ float xs[32][72];
    __shared__ float efs[32][72];
    __shared__ double sc[32][33];

    int tid = threadIdx.x;
    int tl = tid >> 3, eg = tid & 7;
    int tb = blockIdx.x * 32;

    double acc[4] = {0, 0, 0, 0};
    double axx = 0.0;
    int nch = D / 64;

    for (int ch = 0; ch < nch; ++ch) {
        #pragma unroll
        for (int t = 0; t < 2; ++t) {
            int id = t * 256 + tid;
            int r = id >> 4, q = id & 15;
            float4 v = *(const float4*)&x[(size_t)(tb + r) * D + ch * 64 + q * 4];
            *(float4*)&xs[r][q * 4] = v;
            float4 w = *(const float4*)&ef[(size_t)r * D + ch * 64 + q * 4];
            *(float4*)&efs[r][q * 4] = w;
        }
        __syncthreads();
        #pragma unroll 4
        for (int q = 0; q < 16; ++q) {
            float4 xv = *(const float4*)&xs[tl][q * 4];
            double x0 = xv.x, x1 = xv.y, x2 = xv.z, x3 = xv.w;
            axx = fma(x0, x0, fma(x1, x1, fma(x2, x2, fma(x3, x3, axx))));
            #pragma unroll
            for (int j = 0; j < 4; ++j) {
                float4 ev = *(const float4*)&efs[eg + 8 * j][q * 4];
                acc[j] = fma(x0, (double)ev.x, acc[j]);
                acc[j] = fma(x1, (double)ev.y, acc[j]);
                acc[j] = fma(x2, (double)ev.z, acc[j]);
                acc[j] = fma(x3, (double)ev.w, acc[j]);
            }
        }
        __syncthreads();
    }

    double xn = fmax(sqrt(axx), 1e-8);
    #pragma unroll
    for (int j = 0; j < 4; ++j) {
        int e = eg + 8 * j;
        double en = fmax(efn[e], 1e-8);
        double cosv = acc[j] / (xn * en);
        sc[tl][e] = 0.4 * (double)trust[e] + 0.2 * (cosv + 1.0)
                  + 0.2 * fmax(0.0, 1.0 - (double)stale[e]);
    }
    __syncthreads();

    if (tid < 32) {
        int kk = kp[0]; kk = kk < 1 ? 1 : (kk > KMAX ? KMAX : kk);
        unsigned mask = 0;
        int t = tb + tid;
        for (int p = 0; p < kk; ++p) {
            double bv = -1e300; int be = 0;
            #pragma unroll
            for (int e = 0; e < 32; ++e) {
                double v = sc[tid][e];
                if (!((mask >> e) & 1u) && v > bv) { bv = v; be = e; }
            }
            mask |= 1u << be;
            int pos = atomicAdd(&counts[be * CSTRIDE], 1);
            lists[(size_t)be * B + pos] = t;
        }
    }
}

__global__ __launch_bounds__(512) void k_moe_f32(
    const float* __restrict__ x, const float* __restrict__ W,
    const float* __restrict__ bias, const int* __restrict__ lists,
    const int* __restrict__ counts, const int* __restrict__ kp,
    int B, int C, int D, float* __restrict__ out)
{
    int e = blockIdx.z;
    int cnt = counts[e * CSTRIDE];
    int row0 = blockIdx.x * 128;
    if (row0 >= cnt) return;
    int col0 = blockIdx.y * 256;
    int nt = min(128, cnt - row0);

    __shared__ ushort xs[128 * 72];
    __shared__ ushort wsh[256 * 72];
    __shared__ int toks[128];

    int tid = threadIdx.x;
    if (tid < 128) toks[tid] = (tid < nt) ? lists[(size_t)e * B + row0 + tid] : 0;
    __syncthreads();

    int lane = tid & 63, wid = tid >> 6;
    int wr = wid >> 2, wc = wid & 3;
    int l15 = lane & 15, l16 = lane >> 4;

    f32x4 acc[4][4];
    #pragma unroll
    for (int m = 0; m < 4; ++m)
        #pragma unroll
        for (int n = 0; n < 4; ++n) acc[m][n] = (f32x4){0.f, 0.f, 0.f, 0.f};

    int nch = D / 64;
    for (int ch = 0; ch < nch; ++ch) {
        int k0 = ch * 64;
        #pragma unroll
        for (int t = 0; t < 4; ++t) {
            int id = t * 512 + tid;
            int r = id >> 4, q = id & 15;
            float4 v = (r < nt)
                ? *(const float4*)&x[(size_t)toks[r] * D + k0 + q * 4]
                : make_float4(0.f, 0.f, 0.f, 0.f);
            ushort4 u;
            u.x = f2bf(v.x); u.y = f2bf(v.y); u.z = f2bf(v.z); u.w = f2bf(v.w);
            *(ushort4*)&xs[r * 72 + q * 4] = u;
        }
        #pragma unroll
        for (int t = 0; t < 8; ++t) {
            int id = t * 512 + tid;
            int r = id >> 4, q = id & 15;
            float4 v = *(const float4*)&W[((size_t)e * C + col0 + r) * D + k0 + q * 4];
            ushort4 u;
            u.x = f2bf(v.x); u.y = f2bf(v.y); u.z = f2bf(v.z); u.w = f2bf(v.w);
            *(ushort4*)&wsh[r * 72 + q * 4] = u;
        }
        __syncthreads();
        #pragma unroll
        for (int ks = 0; ks < 2; ++ks) {
            s16x8 a[4], bfr[4];
            #pragma unroll
            for (int m = 0; m < 4; ++m)
                a[m] = *(const s16x8*)&xs[(wr * 64 + m * 16 + l15) * 72 + ks * 32 + l16 * 8];
            #pragma unroll
            for (int n = 0; n < 4; ++n)
                bfr[n] = *(const s16x8*)&wsh[(wc * 64 + n * 16 + l15) * 72 + ks * 32 + l16 * 8];
            #pragma unroll
            for (int m = 0; m < 4; ++m)
                #pragma unroll
                for (int n = 0; n < 4; ++n)
                    acc[m][n] = __builtin_amdgcn_mfma_f32_16x16x32_bf16(
                        a[m], bfr[n], acc[m][n], 0, 0, 0);
        }
        __syncthreads();
    }

    int kk = kp[0]; kk = kk < 1 ? 1 : (kk > KMAX ? KMAX : kk);
    float invk = 1.0f / (float)kk;
    #pragma unroll
    for (int m = 0; m < 4; ++m) {
        int rbase = wr * 64 + m * 16 + l16 * 4;
        #pragma unroll
        for (int n = 0; n < 4; ++n) {
            int col = col0 + wc * 64 + n * 16 + l15;
            float bv = bias[(size_t)e * C + col];
            #pragma unroll
            for (int r = 0; r < 4; ++r) {
                int rl = rbase + r;
                if (rl < nt)
                    atomicAdd(&out[(size_t)toks[rl] * C + col],
                              invk * (acc[m][n][r] + bv));
            }
        }
    }
}

// ---------------------------------------------------------------------------
extern "C" void kernel_launch(void* const* d_in, const int* in_sizes, int n_in,
                              void* d_out, int out_size, void* d_ws, size_t ws_size,
                              hipStream_t stream) {
    const float* x     = (const float*)d_in[0];
    const float* ef    = (const float*)d_in[1];
    const float* trust = (const float*)d_in[2];
    const float* stale = (const float*)d_in[3];
    const float* W     = (const float*)d_in[4];
    const float* b     = (const float*)d_in[5];
    const int*   kp    = (const int*)d_in[6];

    int E = in_sizes[2];            // 32
    int D = in_sizes[1] / E;        // 1024
    int B = in_sizes[0] / D;        // 8192
    int C = in_sizes[5] / E;        // 256
    float* out = (float*)d_out;

    // workspace layout
    char* ws = (char*)d_ws;
    double* efn   = (double*)ws;                       // 256 B (legacy path)
    int*    counts= (int*)(ws + 256);                  // 32*CSTRIDE*4 = 8 KB
    size_t off_sel = 256 + 32 * CSTRIDE * 4 + 256;
    int*    sel   = (int*)(ws + off_sel);              // B*KMAX*4
    size_t off_lists = off_sel + (size_t)B * KMAX * 4;
    int*    lists = (int*)(ws + off_lists);            // E*B*4
    size_t off_xbf = off_lists + (size_t)E * B * 4;
    off_xbf = (off_xbf + 255) & ~(size_t)255;
    ushort* xbf = (ushort*)(ws + off_xbf);             // B*D*2
    size_t off_wbf = off_xbf + (size_t)B * D * 2;
    ushort* wbf = (ushort*)(ws + off_wbf);             // E*C*D*2
    size_t off_part = off_wbf + (size_t)E * C * D * 2;
    off_part = (off_part + 255) & ~(size_t)255;
    ushort* part = (ushort*)(ws + off_part);           // B*KMAX*C*2 bf16 slots
    size_t need_mid  = off_part;
    size_t need_full = off_part + (size_t)B * KMAX * C * 2;

    bool fullPath = ws_size >= need_mid;
    int usePart = (fullPath && ws_size >= need_full) ? 1 : 0;

    hipMemsetAsync(counts, 0, 32 * CSTRIDE * 4, stream);
    if (!usePart)
        hipMemsetAsync(d_out, 0, (size_t)out_size * sizeof(float), stream);

    if (fullPath) {
        int nSB = B / 16;                                // 512 scores blocks
        int bpe = ((C * D) / 4 + 1023) / 1024;           // W-conv blocks/expert
        int nWB = E * bpe;                               // 2048
        k_fused<<<nSB + nWB, 256, 0, stream>>>(
            x, ef, trust, stale, W, kp, D, B, C, nSB, bpe,
            xbf, wbf, counts, lists, sel);
        dim3 grid((B + 127) / 128, C / 128, E);
        k_moe3<<<grid, 512, 0, stream>>>(xbf, wbf, b, lists, counts, kp,
                                         B, C, D, usePart, part, out);
        if (usePart)
            k_combine<<<B / 4, 256, 0, stream>>>(part, sel, counts, kp, C, out);
    } else {
        k_efnorm<<<E, 64, 0, stream>>>(ef, D, efn);
        k_scores_legacy<<<B / 32, 256, 0, stream>>>(x, ef, trust, stale, efn,
                                                    kp, D, B, counts, lists);
        dim3 grid((B + 127) / 128, C / 256, E);
        k_moe_f32<<<grid, 512, 0, stream>>>(x, W, b, lists, counts, kp,
                                            B, C, D, out);
    }
}

// Round 14
// 91.051 us; speedup vs baseline: 1.0275x; 1.0275x over previous
//
#include <hip/hip_runtime.h>
#include <math.h>

#define KMAX 8
#define CSTRIDE 64   // ints between expert counters = 256 B -> distinct cache lines

typedef short s16x8 __attribute__((ext_vector_type(8)));
typedef float f32x4 __attribute__((ext_vector_type(4)));

__device__ inline ushort f2bf(float f) {
    union { float f; unsigned u; } v; v.f = f;
    unsigned r = v.u + 0x7fffu + ((v.u >> 16) & 1u);   // RNE
    return (ushort)(r >> 16);
}
__device__ inline float bf2f(ushort b) {
    union { unsigned u; float f; } v; v.u = ((unsigned)b) << 16; return v.f;
}

__device__ inline void gload_lds16(const void* g, void* l) {
    __builtin_amdgcn_global_load_lds(
        (const __attribute__((address_space(1))) unsigned int*)g,
        (__attribute__((address_space(3))) unsigned int*)l, 16, 0, 0);
}

// ---------------------------------------------------------------------------
// K0: per-expert feature norms in double + counts zeroing (no memset node).
// grid = E blocks of 64 threads.  Used by BOTH paths.
// ---------------------------------------------------------------------------
__global__ void k_efnorm(const float* __restrict__ ef, int D,
                         double* __restrict__ efn, int* __restrict__ counts) {
    int e = blockIdx.x;
    int lane = threadIdx.x;  // 64
    if (lane == 0) counts[e * CSTRIDE] = 0;
    double s = 0.0;
    for (int i = lane; i < D; i += 64) {
        double v = (double)ef[(size_t)e * D + i];
        s = fma(v, v, s);
    }
    #pragma unroll
    for (int off = 32; off > 0; off >>= 1) s += __shfl_xor(s, off);
    if (lane == 0) efn[e] = sqrt(s);
}

// ---------------------------------------------------------------------------
// K_fused: blocks [0, nSB) = round-12's EXACT scores+top-k+scatter (+x->bf16
// mirror), reading efn[] (the round-13 per-block ef-norm recompute regressed
// 60% via +67% inner-loop VALU — reverted); blocks [nSB, nSB+E*bpe) =
// UNGATED W->bf16 conversion, co-launched because same-stream kernels
// serialize — this is the only way W-conv overlaps the latency-bound scores
// phase.  No dependency between the two block families (G16-safe).
// ---------------------------------------------------------------------------
__global__ __launch_bounds__(256) void k_fused(
    const float* __restrict__ x, const float* __restrict__ ef,
    const float* __restrict__ trust, const float* __restrict__ stale,
    const float* __restrict__ W, const double* __restrict__ efn,
    const int* __restrict__ kp,
    int D, int B, int C, int nSB, int bpe,
    ushort* __restrict__ xbf, ushort* __restrict__ wbf,
    int* __restrict__ counts, int* __restrict__ lists, int* __restrict__ sel)
{
    __shared__ float xs[16 * 64];           // 4 KB
    __shared__ float efs[32 * 64];          // 8 KB
    __shared__ double sc[16 * 33];
    __shared__ int bcnt[32];
    __shared__ int bbase[32];
    __shared__ unsigned char selb[16 * KMAX];
    __shared__ unsigned char lposb[16 * KMAX];

    int tid = threadIdx.x;

    // ---------------- W-conversion blocks (ungated, overlap scores) --------
    if ((int)blockIdx.x >= nSB) {
        int wb = blockIdx.x - nSB;
        int e = wb / bpe, sub = wb % bpe;
        int perExpF4 = (C * D) / 4;
        size_t base = (size_t)e * perExpF4;
        #pragma unroll
        for (int j = 0; j < 4; ++j) {
            int idx = (sub * 4 + j) * 256 + tid;
            if (idx < perExpF4) {
                float4 v = *(const float4*)&W[(base + idx) * 4];
                ushort4 u;
                u.x = f2bf(v.x); u.y = f2bf(v.y);
                u.z = f2bf(v.z); u.w = f2bf(v.w);
                *(ushort4*)&wbf[(base + idx) * 4] = u;
            }
        }
        return;
    }

    // ---------------- scores blocks (round-12 proven structure) ------------
    int tp = tid >> 4, eg = tid & 15;
    int tb = blockIdx.x * 16;

    if (tid < 32) bcnt[tid] = 0;

    int rx = tid >> 4, qx = tid & 15;
    int re0 = tid >> 4, re1 = 16 + (tid >> 4);
    int qe = tid & 15;

    int nch = D / 64;

    float4 vx  = *(const float4*)&x[(size_t)(tb + rx) * D + qx * 4];
    float4 ve0 = *(const float4*)&ef[(size_t)re0 * D + qe * 4];
    float4 ve1 = *(const float4*)&ef[(size_t)re1 * D + qe * 4];

    double acc0 = 0.0, acc1 = 0.0, axx = 0.0;

    for (int ch = 0; ch < nch; ++ch) {
        *(float4*)&xs[rx * 64 + ((qx ^ rx) << 2)] = vx;
        {
            ushort4 u;
            u.x = f2bf(vx.x); u.y = f2bf(vx.y); u.z = f2bf(vx.z); u.w = f2bf(vx.w);
            *(ushort4*)&xbf[(size_t)(tb + rx) * D + ch * 64 + qx * 4] = u;
        }
        *(float4*)&efs[re0 * 64 + ((qe ^ (re0 & 15)) << 2)] = ve0;
        *(float4*)&efs[re1 * 64 + ((qe ^ (re1 & 15)) << 2)] = ve1;
        __syncthreads();

        // T14: issue NEXT chunk's loads before compute
        if (ch + 1 < nch) {
            int k1 = (ch + 1) * 64;
            vx  = *(const float4*)&x[(size_t)(tb + rx) * D + k1 + qx * 4];
            ve0 = *(const float4*)&ef[(size_t)re0 * D + k1 + qe * 4];
            ve1 = *(const float4*)&ef[(size_t)re1 * D + k1 + qe * 4];
        }

        float a0 = 0.f, a1 = 0.f, ax = 0.f;
        #pragma unroll
        for (int q = 0; q < 16; ++q) {
            float4 xv = *(const float4*)&xs[tp * 64 + ((q ^ tp) << 2)];
            float4 e0 = *(const float4*)&efs[eg * 64 + ((q ^ eg) << 2)];
            float4 e1 = *(const float4*)&efs[(eg + 16) * 64 + ((q ^ eg) << 2)];
            a0 = fmaf(xv.x, e0.x, a0); a0 = fmaf(xv.y, e0.y, a0);
            a0 = fmaf(xv.z, e0.z, a0); a0 = fmaf(xv.w, e0.w, a0);
            a1 = fmaf(xv.x, e1.x, a1); a1 = fmaf(xv.y, e1.y, a1);
            a1 = fmaf(xv.z, e1.z, a1); a1 = fmaf(xv.w, e1.w, a1);
            ax = fmaf(xv.x, xv.x, ax); ax = fmaf(xv.y, xv.y, ax);
            ax = fmaf(xv.z, xv.z, ax); ax = fmaf(xv.w, xv.w, ax);
        }
        __syncthreads();
        acc0 += (double)a0; acc1 += (double)a1; axx += (double)ax;
    }

    double xn = fmax(sqrt(axx), 1e-8);
    {
        int e0i = eg;
        double en0 = fmax(efn[e0i], 1e-8);
        sc[tp * 33 + e0i] = 0.4 * (double)trust[e0i]
            + 0.2 * (acc0 / (xn * en0) + 1.0)
            + 0.2 * fmax(0.0, 1.0 - (double)stale[e0i]);
        int e1i = eg + 16;
        double en1 = fmax(efn[e1i], 1e-8);
        sc[tp * 33 + e1i] = 0.4 * (double)trust[e1i]
            + 0.2 * (acc1 / (xn * en1) + 1.0)
            + 0.2 * fmax(0.0, 1.0 - (double)stale[e1i]);
    }
    __syncthreads();

    int kk = kp[0]; kk = kk < 1 ? 1 : (kk > KMAX ? KMAX : kk);

    // per-token top-k (strict > scan, lowest-index tie-break == jax.lax.top_k
    // selected set); hierarchical scatter (round-4 fix)
    if (tid < 16) {
        unsigned mask = 0;
        for (int p = 0; p < kk; ++p) {
            double bv = -1e300; int be = 0;
            #pragma unroll
            for (int e = 0; e < 32; ++e) {
                double v = sc[tid * 33 + e];
                if (!((mask >> e) & 1u) && v > bv) { bv = v; be = e; }
            }
            mask |= 1u << be;
            selb[tid * KMAX + p] = (unsigned char)be;
            lposb[tid * KMAX + p] = (unsigned char)atomicAdd(&bcnt[be], 1);
        }
    }
    __syncthreads();
    if (tid < 32) {
        int c = bcnt[tid];
        bbase[tid] = c ? atomicAdd(&counts[tid * CSTRIDE], c) : 0;
    }
    __syncthreads();
    if (tid < 16) {
        int t = tb + tid;
        for (int p = 0; p < kk; ++p) {
            int e = selb[tid * KMAX + p];
            int pos = bbase[e] + lposb[tid * KMAX + p];
            lists[(size_t)e * B + pos] = t;
            sel[(size_t)t * KMAX + p] = (e << 24) | pos;
        }
    }
}

// ---------------------------------------------------------------------------
// K4 v3: grouped expert GEMM (round-10 proven — BM=128, BN=128, 512 threads
// = 8 waves, wave tile 32x64, single-buffer 2-barrier K-loop, XOR swizzle
// both sides -> 0 conflicts, bf16 part stores / atomic fallback).
// offs[e] prefix-scan computed inline (32 uniform L2 loads, scalar).
// ---------------------------------------------------------------------------
__global__ __launch_bounds__(512) void k_moe3(
    const ushort* __restrict__ xbf, const ushort* __restrict__ wbf,
    const float* __restrict__ bias, const int* __restrict__ lists,
    const int* __restrict__ counts, const int* __restrict__ kp,
    int B, int C, int D, int usePart,
    ushort* __restrict__ part, float* __restrict__ out)
{
    int e = blockIdx.z;
    int cnt = counts[e * CSTRIDE];
    int row0 = blockIdx.x * 128;
    if (row0 >= cnt) return;            // uniform: safe before barriers
    int col0 = blockIdx.y * 128;
    int nt = min(128, cnt - row0);

    __shared__ ushort xs[128 * 64];     // 16 KB
    __shared__ ushort wsh[128 * 64];    // 16 KB
    __shared__ int toks[128];

    int tid = threadIdx.x;
    if (tid < 128) toks[tid] = (tid < nt) ? lists[(size_t)e * B + row0 + tid] : 0;
    __syncthreads();

    int lane = tid & 63, wid = tid >> 6;
    int wr = wid >> 1, wc = wid & 1;    // wave tile: rows wr*32, cols wc*64
    int l15 = lane & 15, l16 = lane >> 4;

    f32x4 acc[2][4];
    #pragma unroll
    for (int m = 0; m < 2; ++m)
        #pragma unroll
        for (int n = 0; n < 4; ++n) acc[m][n] = (f32x4){0.f, 0.f, 0.f, 0.f};

    int nch = D / 64;
    for (int ch = 0; ch < nch; ++ch) {
        int k0 = ch * 64;
        #pragma unroll
        for (int t = 0; t < 2; ++t) {
            int id = t * 512 + tid;
            int r = id >> 3, seg = id & 7;
            int ssw = (seg ^ (r & 7)) << 3;
            gload_lds16(&xbf[(size_t)toks[r] * D + k0 + ssw],
                        (char*)xs + (size_t)(t * 512 + wid * 64) * 16);
        }
        #pragma unroll
        for (int t = 0; t < 2; ++t) {
            int id = t * 512 + tid;
            int r = id >> 3, seg = id & 7;
            int ssw = (seg ^ (r & 7)) << 3;
            gload_lds16(&wbf[((size_t)e * C + col0 + r) * D + k0 + ssw],
                        (char*)wsh + (size_t)(t * 512 + wid * 64) * 16);
        }
        __syncthreads();
        #pragma unroll
        for (int ks = 0; ks < 2; ++ks) {
            s16x8 a[2], bfr[4];
            int sbase = ks * 4 + l16;
            #pragma unroll
            for (int m = 0; m < 2; ++m) {
                int r = wr * 32 + m * 16 + l15;
                a[m] = *(const s16x8*)&xs[r * 64 + ((sbase ^ (l15 & 7)) << 3)];
            }
            #pragma unroll
            for (int n = 0; n < 4; ++n) {
                int r = wc * 64 + n * 16 + l15;
                bfr[n] = *(const s16x8*)&wsh[r * 64 + ((sbase ^ (l15 & 7)) << 3)];
            }
            #pragma unroll
            for (int m = 0; m < 2; ++m)
                #pragma unroll
                for (int n = 0; n < 4; ++n)
                    acc[m][n] = __builtin_amdgcn_mfma_f32_16x16x32_bf16(
                        a[m], bfr[n], acc[m][n], 0, 0, 0);
        }
        __syncthreads();
    }

    int kk = kp[0]; kk = kk < 1 ? 1 : (kk > KMAX ? KMAX : kk);
    // C/D layout (m89): col = lane&15, row = (lane>>4)*4 + reg
    if (usePart) {
        int offE = 0;
        for (int e2 = 0; e2 < e; ++e2) offE += counts[e2 * CSTRIDE];
        int slotBase = offE + row0;
        #pragma unroll
        for (int m = 0; m < 2; ++m) {
            int rbase = wr * 32 + m * 16 + l16 * 4;
            #pragma unroll
            for (int n = 0; n < 4; ++n) {
                int col = col0 + wc * 64 + n * 16 + l15;
                float bv = bias[(size_t)e * C + col];
                #pragma unroll
                for (int r = 0; r < 4; ++r) {
                    int rl = rbase + r;
                    if (rl < nt)
                        part[(size_t)(slotBase + rl) * C + col] =
                            f2bf(acc[m][n][r] + bv);
                }
            }
        }
    } else {
        float invk = 1.0f / (float)kk;
        #pragma unroll
        for (int m = 0; m < 2; ++m) {
            int rbase = wr * 32 + m * 16 + l16 * 4;
            #pragma unroll
            for (int n = 0; n < 4; ++n) {
                int col = col0 + wc * 64 + n * 16 + l15;
                float bv = bias[(size_t)e * C + col];
                #pragma unroll
                for (int r = 0; r < 4; ++r) {
                    int rl = rbase + r;
                    if (rl < nt)
                        atomicAdd(&out[(size_t)toks[rl] * C + col],
                                  invk * (acc[m][n][r] + bv));
                }
            }
        }
    }
}

// ---------------------------------------------------------------------------
// K5: combine — out[t][c] = (1/k) * sum_p bf2f(part[slot_p*C + c]).
// offs computed inline from counts (wave-uniform scalar loops, L2-hot).
// ---------------------------------------------------------------------------
__global__ __launch_bounds__(256) void k_combine(
    const ushort* __restrict__ part, const int* __restrict__ sel,
    const int* __restrict__ counts, const int* __restrict__ kp,
    int C, float* __restrict__ out)
{
    int kk = kp[0]; kk = kk < 1 ? 1 : (kk > KMAX ? KMAX : kk);
    float invk = 1.0f / (float)kk;
    int sub = threadIdx.x >> 6, lane = threadIdx.x & 63;
    int t = blockIdx.x * 4 + sub;
    int slot[KMAX];
    for (int p = 0; p < kk; ++p) {
        int sv = sel[(size_t)t * KMAX + p];
        int e = sv >> 24;
        int offE = 0;
        for (int e2 = 0; e2 < e; ++e2) offE += counts[e2 * CSTRIDE];
        slot[p] = offE + (sv & 0xFFFFFF);
    }
    for (int c = lane * 4; c < C; c += 256) {
        float s0 = 0.f, s1 = 0.f, s2 = 0.f, s3 = 0.f;
        for (int p = 0; p < kk; ++p) {
            ushort4 u = *(const ushort4*)&part[(size_t)slot[p] * C + c];
            s0 += bf2f(u.x); s1 += bf2f(u.y); s2 += bf2f(u.z); s3 += bf2f(u.w);
        }
        float4 o = make_float4(invk * s0, invk * s1, invk * s2, invk * s3);
        *(float4*)&out[(size_t)t * C + c] = o;
    }
}

// ===========================================================================
// Legacy fallback — only if ws_size is too small for the bf16 mirrors.
// ===========================================================================
__global__ __launch_bounds__(256) void k_scores_legacy(
    const float* __restrict__ x, const float* __restrict__ ef,
    const float* __restrict__ trust, const float* __restrict__ stale,
    const double* __restrict__ efn, const int* __restrict__ kp,
    int D, int B, int* __restrict__ counts, int* __restrict__ lists)
{
    __shared__ float xs[32][72];
    __shared__ float efs[32][72];
    __shared__ double sc[32][33];

    int tid = threadIdx.x;
    int tl = tid >> 3, eg = tid & 7;
    int tb = blockIdx.x * 32;

    double acc[4] = {0, 0, 0, 0};
    double axx = 0.0;
    int nch = D / 64;

    for (int ch = 0; ch < nch; ++ch) {
        #pragma unroll
        for (int t = 0; t < 2; ++t) {
            int id = t * 256 + tid;
            int r = id >> 4, q = id & 15;
            float4 v = *(const float4*)&x[(size_t)(tb + r) * D + ch * 64 + q * 4];
            *(float4*)&xs[r][q * 4] = v;
            float4 w = *(const float4*)&ef[(size_t)r * D + ch * 64 + q * 4];
            *(float4*)&efs[r][q * 4] = w;
        }
        __syncthreads();
        #pragma unroll 4
        for (int q = 0; q < 16; ++q) {
            float4 xv = *(const float4*)&xs[tl][q * 4];
            double x0 = xv.x, x1 = xv.y, x2 = xv.z, x3 = xv.w;
            axx = fma(x0, x0, fma(x1, x1, fma(x2, x2, fma(x3, x3, axx))));
            #pragma unroll
            for (int j = 0; j < 4; ++j) {
                float4 ev = *(const float4*)&efs[eg + 8 * j][q * 4];
                acc[j] = fma(x0, (double)ev.x, acc[j]);
                acc[j] = fma(x1, (double)ev.y, acc[j]);
                acc[j] = fma(x2, (double)ev.z, acc[j]);
                acc[j] = fma(x3, (double)ev.w, acc[j]);
            }
        }
        __syncthreads();
    }

    double xn = fmax(sqrt(axx), 1e-8);
    #pragma unroll
    for (int j = 0; j < 4; ++j) {
        int e = eg + 8 * j;
        double en = fmax(efn[e], 1e-8);
        double cosv = acc[j] / (xn * en);
        sc[tl][e] = 0.4 * (double)trust[e] + 0.2 * (cosv + 1.0)
                  + 0.2 * fmax(0.0, 1.0 - (double)stale[e]);
    }
    __syncthreads();

    if (tid < 32) {
        int kk = kp[0]; kk = kk < 1 ? 1 : (kk > KMAX ? KMAX : kk);
        unsigned mask = 0;
        int t = tb + tid;
        for (int p = 0; p < kk; ++p) {
            double bv = -1e300; int be = 0;
            #pragma unroll
            for (int e = 0; e < 32; ++e) {
                double v = sc[tid][e];
                if (!((mask >> e) & 1u) && v > bv) { bv = v; be = e; }
            }
            mask |= 1u << be;
            int pos = atomicAdd(&counts[be * CSTRIDE], 1);
            lists[(size_t)be * B + pos] = t;
        }
    }
}

__global__ __launch_bounds__(512) void k_moe_f32(
    const float* __restrict__ x, const float* __restrict__ W,
    const float* __restrict__ bias, const int* __restrict__ lists,
    const int* __restrict__ counts, const int* __restrict__ kp,
    int B, int C, int D, float* __restrict__ out)
{
    int e = blockIdx.z;
    int cnt = counts[e * CSTRIDE];
    int row0 = blockIdx.x * 128;
    if (row0 >= cnt) return;
    int col0 = blockIdx.y * 256;
    int nt = min(128, cnt - row0);

    __shared__ ushort xs[128 * 72];
    __shared__ ushort wsh[256 * 72];
    __shared__ int toks[128];

    int tid = threadIdx.x;
    if (tid < 128) toks[tid] = (tid < nt) ? lists[(size_t)e * B + row0 + tid] : 0;
    __syncthreads();

    int lane = tid & 63, wid = tid >> 6;
    int wr = wid >> 2, wc = wid & 3;
    int l15 = lane & 15, l16 = lane >> 4;

    f32x4 acc[4][4];
    #pragma unroll
    for (int m = 0; m < 4; ++m)
        #pragma unroll
        for (int n = 0; n < 4; ++n) acc[m][n] = (f32x4){0.f, 0.f, 0.f, 0.f};

    int nch = D / 64;
    for (int ch = 0; ch < nch; ++ch) {
        int k0 = ch * 64;
        #pragma unroll
        for (int t = 0; t < 4; ++t) {
            int id = t * 512 + tid;
            int r = id >> 4, q = id & 15;
            float4 v = (r < nt)
                ? *(const float4*)&x[(size_t)toks[r] * D + k0 + q * 4]
                : make_float4(0.f, 0.f, 0.f, 0.f);
            ushort4 u;
            u.x = f2bf(v.x); u.y = f2bf(v.y); u.z = f2bf(v.z); u.w = f2bf(v.w);
            *(ushort4*)&xs[r * 72 + q * 4] = u;
        }
        #pragma unroll
        for (int t = 0; t < 8; ++t) {
            int id = t * 512 + tid;
            int r = id >> 4, q = id & 15;
            float4 v = *(const float4*)&W[((size_t)e * C + col0 + r) * D + k0 + q * 4];
            ushort4 u;
            u.x = f2bf(v.x); u.y = f2bf(v.y); u.z = f2bf(v.z); u.w = f2bf(v.w);
            *(ushort4*)&wsh[r * 72 + q * 4] = u;
        }
        __syncthreads();
        #pragma unroll
        for (int ks = 0; ks < 2; ++ks) {
            s16x8 a[4], bfr[4];
            #pragma unroll
            for (int m = 0; m < 4; ++m)
                a[m] = *(const s16x8*)&xs[(wr * 64 + m * 16 + l15) * 72 + ks * 32 + l16 * 8];
            #pragma unroll
            for (int n = 0; n < 4; ++n)
                bfr[n] = *(const s16x8*)&wsh[(wc * 64 + n * 16 + l15) * 72 + ks * 32 + l16 * 8];
            #pragma unroll
            for (int m = 0; m < 4; ++m)
                #pragma unroll
                for (int n = 0; n < 4; ++n)
                    acc[m][n] = __builtin_amdgcn_mfma_f32_16x16x32_bf16(
                        a[m], bfr[n], acc[m][n], 0, 0, 0);
        }
        __syncthreads();
    }

    int kk = kp[0]; kk = kk < 1 ? 1 : (kk > KMAX ? KMAX : kk);
    float invk = 1.0f / (float)kk;
    #pragma unroll
    for (int m = 0; m < 4; ++m) {
        int rbase = wr * 64 + m * 16 + l16 * 4;
        #pragma unroll
        for (int n = 0; n < 4; ++n) {
            int col = col0 + wc * 64 + n * 16 + l15;
            float bv = bias[(size_t)e * C + col];
            #pragma unroll
            for (int r = 0; r < 4; ++r) {
                int rl = rbase + r;
                if (rl < nt)
                    atomicAdd(&out[(size_t)toks[rl] * C + col],
                              invk * (acc[m][n][r] + bv));
            }
        }
    }
}

// ---------------------------------------------------------------------------
extern "C" void kernel_launch(void* const* d_in, const int* in_sizes, int n_in,
                              void* d_out, int out_size, void* d_ws, size_t ws_size,
                              hipStream_t stream) {
    const float* x     = (const float*)d_in[0];
    const float* ef    = (const float*)d_in[1];
    const float* trust = (const float*)d_in[2];
    const float* stale = (const float*)d_in[3];
    const float* W     = (const float*)d_in[4];
    const float* b     = (const float*)d_in[5];
    const int*   kp    = (const int*)d_in[6];

    int E = in_sizes[2];            // 32
    int D = in_sizes[1] / E;        // 1024
    int B = in_sizes[0] / D;        // 8192
    int C = in_sizes[5] / E;        // 256
    float* out = (float*)d_out;

    // workspace layout
    char* ws = (char*)d_ws;
    double* efn   = (double*)ws;                       // 256 B
    int*    counts= (int*)(ws + 256);                  // 32*CSTRIDE*4 = 8 KB
    size_t off_sel = 256 + 32 * CSTRIDE * 4 + 256;
    int*    sel   = (int*)(ws + off_sel);              // B*KMAX*4
    size_t off_lists = off_sel + (size_t)B * KMAX * 4;
    int*    lists = (int*)(ws + off_lists);            // E*B*4
    size_t off_xbf = off_lists + (size_t)E * B * 4;
    off_xbf = (off_xbf + 255) & ~(size_t)255;
    ushort* xbf = (ushort*)(ws + off_xbf);             // B*D*2
    size_t off_wbf = off_xbf + (size_t)B * D * 2;
    ushort* wbf = (ushort*)(ws + off_wbf);             // E*C*D*2
    size_t off_part = off_wbf + (size_t)E * C * D * 2;
    off_part = (off_part + 255) & ~(size_t)255;
    ushort* part = (ushort*)(ws + off_part);           // B*KMAX*C*2 bf16 slots
    size_t need_mid  = off_part;
    size_t need_full = off_part + (size_t)B * KMAX * C * 2;

    bool fullPath = ws_size >= need_mid;
    int usePart = (fullPath && ws_size >= need_full) ? 1 : 0;

    if (!usePart)
        hipMemsetAsync(d_out, 0, (size_t)out_size * sizeof(float), stream);

    k_efnorm<<<E, 64, 0, stream>>>(ef, D, efn, counts);  // also zeroes counts

    if (fullPath) {
        int nSB = B / 16;                                // 512 scores blocks
        int bpe = ((C * D) / 4 + 1023) / 1024;           // W-conv blocks/expert
        int nWB = E * bpe;                               // 2048
        k_fused<<<nSB + nWB, 256, 0, stream>>>(
            x, ef, trust, stale, W, efn, kp, D, B, C, nSB, bpe,
            xbf, wbf, counts, lists, sel);
        dim3 grid((B + 127) / 128, C / 128, E);
        k_moe3<<<grid, 512, 0, stream>>>(xbf, wbf, b, lists, counts, kp,
                                         B, C, D, usePart, part, out);
        if (usePart)
            k_combine<<<B / 4, 256, 0, stream>>>(part, sel, counts, kp, C, out);
    } else {
        k_scores_legacy<<<B / 32, 256, 0, stream>>>(x, ef, trust, stale, efn,
                                                    kp, D, B, counts, lists);
        dim3 grid((B + 127) / 128, C / 256, E);
        k_moe_f32<<<grid, 512, 0, stream>>>(x, W, b, lists, counts, kp,
                                            B, C, D, out);
    }
}

// Round 15
// 84.072 us; speedup vs baseline: 1.1128x; 1.0830x over previous
//
#include <hip/hip_runtime.h>
#include <math.h>

#define KMAX 8
#define CSTRIDE 64   // ints between expert counters = 256 B -> distinct cache lines

typedef short s16x8 __attribute__((ext_vector_type(8)));
typedef float f32x4 __attribute__((ext_vector_type(4)));

__device__ inline ushort f2bf(float f) {
    union { float f; unsigned u; } v; v.f = f;
    unsigned r = v.u + 0x7fffu + ((v.u >> 16) & 1u);   // RNE
    return (ushort)(r >> 16);
}
__device__ inline float bf2f(ushort b) {
    union { unsigned u; float f; } v; v.u = ((unsigned)b) << 16; return v.f;
}

__device__ inline void gload_lds16(const void* g, void* l) {
    __builtin_amdgcn_global_load_lds(
        (const __attribute__((address_space(1))) unsigned int*)g,
        (__attribute__((address_space(3))) unsigned int*)l, 16, 0, 0);
}

// ---------------------------------------------------------------------------
// K0: per-expert feature norms in double + counts zeroing (replaces the
// hipMemsetAsync graph node).  grid = E blocks of 64 threads.
// ---------------------------------------------------------------------------
__global__ void k_efnorm(const float* __restrict__ ef, int D,
                         double* __restrict__ efn, int* __restrict__ counts) {
    int e = blockIdx.x;
    int lane = threadIdx.x;  // 64
    if (lane == 0) counts[e * CSTRIDE] = 0;
    double s = 0.0;
    for (int i = lane; i < D; i += 64) {
        double v = (double)ef[(size_t)e * D + i];
        s = fma(v, v, s);
    }
    #pragma unroll
    for (int off = 32; off > 0; off >>= 1) s += __shfl_xor(s, off);
    if (lane == 0) efn[e] = sqrt(s);
}

// ---------------------------------------------------------------------------
// K2: W -> bf16, GATED on counts[e] > 0 (only the ~5 selected experts get
// converted — the round-13/14 ungated co-launch converted all 32 and
// regressed); block (0,0) also computes the exclusive prefix scan offs[e].
// ---------------------------------------------------------------------------
__global__ __launch_bounds__(256) void k_prep_w(
    const float* __restrict__ W, const int* __restrict__ counts,
    int perExpF4, ushort* __restrict__ wbf, int* __restrict__ offs) {
    int e = blockIdx.y;
    if (blockIdx.x == 0 && e == 0 && threadIdx.x == 0) {
        int s = 0;
        for (int e2 = 0; e2 < 32; ++e2) { offs[e2] = s; s += counts[e2 * CSTRIDE]; }
    }
    if (counts[e * CSTRIDE] == 0) return;
    size_t base = (size_t)e * perExpF4;
    #pragma unroll
    for (int j = 0; j < 4; ++j) {
        int idx = (blockIdx.x * 4 + j) * 256 + threadIdx.x;
        if (idx < perExpF4) {
            float4 v = *(const float4*)&W[(base + idx) * 4];
            ushort4 u;
            u.x = f2bf(v.x); u.y = f2bf(v.y); u.z = f2bf(v.z); u.w = f2bf(v.w);
            *(ushort4*)&wbf[(base + idx) * 4] = u;
        }
    }
}

// ---------------------------------------------------------------------------
// K3 (round-12 proven, chunk width 64): scores + top-k + scatter + x->bf16
// mirror + sel[] slot map.  16 tokens/block, 256 threads, B/16 = 512 blocks.
// T14 async-stage split (next chunk to regs before current compute).
// Dots + ||x||^2: f32 chains per 64-chunk, f64 accumulation across chunks
// (tolerance proven rounds 1-14).  Hierarchical scatter (round-4 fix).
// ---------------------------------------------------------------------------
__global__ __launch_bounds__(256) void k_scores3(
    const float* __restrict__ x, const float* __restrict__ ef,
    const float* __restrict__ trust, const float* __restrict__ stale,
    const double* __restrict__ efn, const int* __restrict__ kp,
    int D, int B, ushort* __restrict__ xbf,
    int* __restrict__ counts, int* __restrict__ lists, int* __restrict__ sel)
{
    __shared__ float xs[16 * 64];           // 4 KB
    __shared__ float efs[32 * 64];          // 8 KB
    __shared__ double sc[16 * 33];
    __shared__ int bcnt[32];
    __shared__ int bbase[32];
    __shared__ unsigned char selb[16 * KMAX];
    __shared__ unsigned char lposb[16 * KMAX];

    int tid = threadIdx.x;
    int tp = tid >> 4, eg = tid & 15;
    int tb = blockIdx.x * 16;

    if (tid < 32) bcnt[tid] = 0;

    int rx = tid >> 4, qx = tid & 15;
    int re0 = tid >> 4, re1 = 16 + (tid >> 4);
    int qe = tid & 15;

    int nch = D / 64;

    float4 vx  = *(const float4*)&x[(size_t)(tb + rx) * D + qx * 4];
    float4 ve0 = *(const float4*)&ef[(size_t)re0 * D + qe * 4];
    float4 ve1 = *(const float4*)&ef[(size_t)re1 * D + qe * 4];

    double acc0 = 0.0, acc1 = 0.0, axx = 0.0;

    for (int ch = 0; ch < nch; ++ch) {
        *(float4*)&xs[rx * 64 + ((qx ^ rx) << 2)] = vx;
        {
            ushort4 u;
            u.x = f2bf(vx.x); u.y = f2bf(vx.y); u.z = f2bf(vx.z); u.w = f2bf(vx.w);
            *(ushort4*)&xbf[(size_t)(tb + rx) * D + ch * 64 + qx * 4] = u;
        }
        *(float4*)&efs[re0 * 64 + ((qe ^ (re0 & 15)) << 2)] = ve0;
        *(float4*)&efs[re1 * 64 + ((qe ^ (re1 & 15)) << 2)] = ve1;
        __syncthreads();

        if (ch + 1 < nch) {
            int k1 = (ch + 1) * 64;
            vx  = *(const float4*)&x[(size_t)(tb + rx) * D + k1 + qx * 4];
            ve0 = *(const float4*)&ef[(size_t)re0 * D + k1 + qe * 4];
            ve1 = *(const float4*)&ef[(size_t)re1 * D + k1 + qe * 4];
        }

        float a0 = 0.f, a1 = 0.f, ax = 0.f;
        #pragma unroll
        for (int q = 0; q < 16; ++q) {
            float4 xv = *(const float4*)&xs[tp * 64 + ((q ^ tp) << 2)];
            float4 e0 = *(const float4*)&efs[eg * 64 + ((q ^ eg) << 2)];
            float4 e1 = *(const float4*)&efs[(eg + 16) * 64 + ((q ^ eg) << 2)];
            a0 = fmaf(xv.x, e0.x, a0); a0 = fmaf(xv.y, e0.y, a0);
            a0 = fmaf(xv.z, e0.z, a0); a0 = fmaf(xv.w, e0.w, a0);
            a1 = fmaf(xv.x, e1.x, a1); a1 = fmaf(xv.y, e1.y, a1);
            a1 = fmaf(xv.z, e1.z, a1); a1 = fmaf(xv.w, e1.w, a1);
            ax = fmaf(xv.x, xv.x, ax); ax = fmaf(xv.y, xv.y, ax);
            ax = fmaf(xv.z, xv.z, ax); ax = fmaf(xv.w, xv.w, ax);
        }
        __syncthreads();
        acc0 += (double)a0; acc1 += (double)a1; axx += (double)ax;
    }

    double xn = fmax(sqrt(axx), 1e-8);
    {
        int e0i = eg;
        double en0 = fmax(efn[e0i], 1e-8);
        sc[tp * 33 + e0i] = 0.4 * (double)trust[e0i]
            + 0.2 * (acc0 / (xn * en0) + 1.0)
            + 0.2 * fmax(0.0, 1.0 - (double)stale[e0i]);
        int e1i = eg + 16;
        double en1 = fmax(efn[e1i], 1e-8);
        sc[tp * 33 + e1i] = 0.4 * (double)trust[e1i]
            + 0.2 * (acc1 / (xn * en1) + 1.0)
            + 0.2 * fmax(0.0, 1.0 - (double)stale[e1i]);
    }
    __syncthreads();

    int kk = kp[0]; kk = kk < 1 ? 1 : (kk > KMAX ? KMAX : kk);

    // per-token top-k (strict > scan, lowest-index tie-break == jax.lax.top_k
    // selected set); record selection + LDS-local position
    if (tid < 16) {
        unsigned mask = 0;
        for (int p = 0; p < kk; ++p) {
            double bv = -1e300; int be = 0;
            #pragma unroll
            for (int e = 0; e < 32; ++e) {
                double v = sc[tid * 33 + e];
                if (!((mask >> e) & 1u) && v > bv) { bv = v; be = e; }
            }
            mask |= 1u << be;
            selb[tid * KMAX + p] = (unsigned char)be;
            lposb[tid * KMAX + p] = (unsigned char)atomicAdd(&bcnt[be], 1);
        }
    }
    __syncthreads();
    if (tid < 32) {
        int c = bcnt[tid];
        bbase[tid] = c ? atomicAdd(&counts[tid * CSTRIDE], c) : 0;
    }
    __syncthreads();
    if (tid < 16) {
        int t = tb + tid;
        for (int p = 0; p < kk; ++p) {
            int e = selb[tid * KMAX + p];
            int pos = bbase[e] + lposb[tid * KMAX + p];
            lists[(size_t)e * B + pos] = t;
            sel[(size_t)t * KMAX + p] = (e << 24) | pos;
        }
    }
}

// ---------------------------------------------------------------------------
// K4 v3: grouped expert GEMM (round-10/12 proven — BM=128, BN=128,
// 512 threads = 8 waves, wave tile 32x64, single-buffer 2-barrier K-loop,
// XOR swizzle both sides -> 0 conflicts, bf16 part stores / atomic fallback).
// ---------------------------------------------------------------------------
__global__ __launch_bounds__(512) void k_moe3(
    const ushort* __restrict__ xbf, const ushort* __restrict__ wbf,
    const float* __restrict__ bias, const int* __restrict__ lists,
    const int* __restrict__ counts, const int* __restrict__ offs,
    const int* __restrict__ kp, int B, int C, int D,
    int usePart, ushort* __restrict__ part, float* __restrict__ out)
{
    int e = blockIdx.z;
    int cnt = counts[e * CSTRIDE];
    int row0 = blockIdx.x * 128;
    if (row0 >= cnt) return;            // uniform: safe before barriers
    int col0 = blockIdx.y * 128;
    int nt = min(128, cnt - row0);

    __shared__ ushort xs[128 * 64];     // 16 KB
    __shared__ ushort wsh[128 * 64];    // 16 KB
    __shared__ int toks[128];

    int tid = threadIdx.x;
    if (tid < 128) toks[tid] = (tid < nt) ? lists[(size_t)e * B + row0 + tid] : 0;
    __syncthreads();

    int lane = tid & 63, wid = tid >> 6;
    int wr = wid >> 1, wc = wid & 1;    // wave tile: rows wr*32, cols wc*64
    int l15 = lane & 15, l16 = lane >> 4;

    f32x4 acc[2][4];
    #pragma unroll
    for (int m = 0; m < 2; ++m)
        #pragma unroll
        for (int n = 0; n < 4; ++n) acc[m][n] = (f32x4){0.f, 0.f, 0.f, 0.f};

    int nch = D / 64;
    for (int ch = 0; ch < nch; ++ch) {
        int k0 = ch * 64;
        #pragma unroll
        for (int t = 0; t < 2; ++t) {
            int id = t * 512 + tid;
            int r = id >> 3, seg = id & 7;
            int ssw = (seg ^ (r & 7)) << 3;
            gload_lds16(&xbf[(size_t)toks[r] * D + k0 + ssw],
                        (char*)xs + (size_t)(t * 512 + wid * 64) * 16);
        }
        #pragma unroll
        for (int t = 0; t < 2; ++t) {
            int id = t * 512 + tid;
            int r = id >> 3, seg = id & 7;
            int ssw = (seg ^ (r & 7)) << 3;
            gload_lds16(&wbf[((size_t)e * C + col0 + r) * D + k0 + ssw],
                        (char*)wsh + (size_t)(t * 512 + wid * 64) * 16);
        }
        __syncthreads();
        #pragma unroll
        for (int ks = 0; ks < 2; ++ks) {
            s16x8 a[2], bfr[4];
            int sbase = ks * 4 + l16;
            #pragma unroll
            for (int m = 0; m < 2; ++m) {
                int r = wr * 32 + m * 16 + l15;
                a[m] = *(const s16x8*)&xs[r * 64 + ((sbase ^ (l15 & 7)) << 3)];
            }
            #pragma unroll
            for (int n = 0; n < 4; ++n) {
                int r = wc * 64 + n * 16 + l15;
                bfr[n] = *(const s16x8*)&wsh[r * 64 + ((sbase ^ (l15 & 7)) << 3)];
            }
            #pragma unroll
            for (int m = 0; m < 2; ++m)
                #pragma unroll
                for (int n = 0; n < 4; ++n)
                    acc[m][n] = __builtin_amdgcn_mfma_f32_16x16x32_bf16(
                        a[m], bfr[n], acc[m][n], 0, 0, 0);
        }
        __syncthreads();
    }

    int kk = kp[0]; kk = kk < 1 ? 1 : (kk > KMAX ? KMAX : kk);
    // C/D layout (m89): col = lane&15, row = (lane>>4)*4 + reg
    if (usePart) {
        int slotBase = offs[e] + row0;
        #pragma unroll
        for (int m = 0; m < 2; ++m) {
            int rbase = wr * 32 + m * 16 + l16 * 4;
            #pragma unroll
            for (int n = 0; n < 4; ++n) {
                int col = col0 + wc * 64 + n * 16 + l15;
                float bv = bias[(size_t)e * C + col];
                #pragma unroll
                for (int r = 0; r < 4; ++r) {
                    int rl = rbase + r;
                    if (rl < nt)
                        part[(size_t)(slotBase + rl) * C + col] =
                            f2bf(acc[m][n][r] + bv);
                }
            }
        }
    } else {
        float invk = 1.0f / (float)kk;
        #pragma unroll
        for (int m = 0; m < 2; ++m) {
            int rbase = wr * 32 + m * 16 + l16 * 4;
            #pragma unroll
            for (int n = 0; n < 4; ++n) {
                int col = col0 + wc * 64 + n * 16 + l15;
                float bv = bias[(size_t)e * C + col];
                #pragma unroll
                for (int r = 0; r < 4; ++r) {
                    int rl = rbase + r;
                    if (rl < nt)
                        atomicAdd(&out[(size_t)toks[rl] * C + col],
                                  invk * (acc[m][n][r] + bv));
                }
            }
        }
    }
}

// ---------------------------------------------------------------------------
// K5: combine — out[t][c] = (1/k) * sum_p bf2f(part[slot_p*C + c]).
// ---------------------------------------------------------------------------
__global__ __launch_bounds__(256) void k_combine(
    const ushort* __restrict__ part, const int* __restrict__ sel,
    const int* __restrict__ offs, const int* __restrict__ kp,
    int C, float* __restrict__ out)
{
    int kk = kp[0]; kk = kk < 1 ? 1 : (kk > KMAX ? KMAX : kk);
    float invk = 1.0f / (float)kk;
    int sub = threadIdx.x >> 6, lane = threadIdx.x & 63;
    int t = blockIdx.x * 4 + sub;
    for (int c = lane * 4; c < C; c += 256) {
        float s0 = 0.f, s1 = 0.f, s2 = 0.f, s3 = 0.f;
        for (int p = 0; p < kk; ++p) {
            int sv = sel[(size_t)t * KMAX + p];
            int slot = offs[sv >> 24] + (sv & 0xFFFFFF);
            ushort4 u = *(const ushort4*)&part[(size_t)slot * C + c];
            s0 += bf2f(u.x); s1 += bf2f(u.y); s2 += bf2f(u.z); s3 += bf2f(u.w);
        }
        float4 o = make_float4(invk * s0, invk * s1, invk * s2, invk * s3);
        *(float4*)&out[(size_t)t * C + c] = o;
    }
}

// ===========================================================================
// Legacy fallback — only if ws_size is too small for the bf16 mirrors.
// ===========================================================================
__global__ __launch_bounds__(256) void k_scores_legacy(
    const float* __restrict__ x, const float* __restrict__ ef,
    const float* __restrict__ trust, const float* __restrict__ stale,
    const double* __restrict__ efn, const int* __restrict__ kp,
    int D, int B, int* __restrict__ counts, int* __restrict__ lists)
{
    __shared__ float xs[32][72];
    __shared__ float efs[32][72];
    __shared__ double sc[32][33];

    int tid = threadIdx.x;
    int tl = tid >> 3, eg = tid & 7;
    int tb = blockIdx.x * 32;

    double acc[4] = {0, 0, 0, 0};
    double axx = 0.0;
    int nch = D / 64;

    for (int ch = 0; ch < nch; ++ch) {
        #pragma unroll
        for (int t = 0; t < 2; ++t) {
            int id = t * 256 + tid;
            int r = id >> 4, q = id & 15;
            float4 v = *(const float4*)&x[(size_t)(tb + r) * D + ch * 64 + q * 4];
            *(float4*)&xs[r][q * 4] = v;
            float4 w = *(const float4*)&ef[(size_t)r * D + ch * 64 + q * 4];
            *(float4*)&efs[r][q * 4] = w;
        }
        __syncthreads();
        #pragma unroll 4
        for (int q = 0; q < 16; ++q) {
            float4 xv = *(const float4*)&xs[tl][q * 4];
            double x0 = xv.x, x1 = xv.y, x2 = xv.z, x3 = xv.w;
            axx = fma(x0, x0, fma(x1, x1, fma(x2, x2, fma(x3, x3, axx))));
            #pragma unroll
            for (int j = 0; j < 4; ++j) {
                float4 ev = *(const float4*)&efs[eg + 8 * j][q * 4];
                acc[j] = fma(x0, (double)ev.x, acc[j]);
                acc[j] = fma(x1, (double)ev.y, acc[j]);
                acc[j] = fma(x2, (double)ev.z, acc[j]);
                acc[j] = fma(x3, (double)ev.w, acc[j]);
            }
        }
        __syncthreads();
    }

    double xn = fmax(sqrt(axx), 1e-8);
    #pragma unroll
    for (int j = 0; j < 4; ++j) {
        int e = eg + 8 * j;
        double en = fmax(efn[e], 1e-8);
        double cosv = acc[j] / (xn * en);
        sc[tl][e] = 0.4 * (double)trust[e] + 0.2 * (cosv + 1.0)
                  + 0.2 * fmax(0.0, 1.0 - (double)stale[e]);
    }
    __syncthreads();

    if (tid < 32) {
        int kk = kp[0]; kk = kk < 1 ? 1 : (kk > KMAX ? KMAX : kk);
        unsigned mask = 0;
        int t = tb + tid;
        for (int p = 0; p < kk; ++p) {
            double bv = -1e300; int be = 0;
            #pragma unroll
            for (int e = 0; e < 32; ++e) {
                double v = sc[tid][e];
                if (!((mask >> e) & 1u) && v > bv) { bv = v; be = e; }
            }
            mask |= 1u << be;
            int pos = atomicAdd(&counts[be * CSTRIDE], 1);
            lists[(size_t)be * B + pos] = t;
        }
    }
}

__global__ __launch_bounds__(512) void k_moe_f32(
    const float* __restrict__ x, const float* __restrict__ W,
    const float* __restrict__ bias, const int* __restrict__ lists,
    const int* __restrict__ counts, const int* __restrict__ kp,
    int B, int C, int D, float* __restrict__ out)
{
    int e = blockIdx.z;
    int cnt = counts[e * CSTRIDE];
    int row0 = blockIdx.x * 128;
    if (row0 >= cnt) return;
    int col0 = blockIdx.y * 256;
    int nt = min(128, cnt - row0);

    __shared__ ushort xs[128 * 72];
    __shared__ ushort wsh[256 * 72];
    __shared__ int toks[128];

    int tid = threadIdx.x;
    if (tid < 128) toks[tid] = (tid < nt) ? lists[(size_t)e * B + row0 + tid] : 0;
    __syncthreads();

    int lane = tid & 63, wid = tid >> 6;
    int wr = wid >> 2, wc = wid & 3;
    int l15 = lane & 15, l16 = lane >> 4;

    f32x4 acc[4][4];
    #pragma unroll
    for (int m = 0; m < 4; ++m)
        #pragma unroll
        for (int n = 0; n < 4; ++n) acc[m][n] = (f32x4){0.f, 0.f, 0.f, 0.f};

    int nch = D / 64;
    for (int ch = 0; ch < nch; ++ch) {
        int k0 = ch * 64;
        #pragma unroll
        for (int t = 0; t < 4; ++t) {
            int id = t * 512 + tid;
            int r = id >> 4, q = id & 15;
            float4 v = (r < nt)
                ? *(const float4*)&x[(size_t)toks[r] * D + k0 + q * 4]
                : make_float4(0.f, 0.f, 0.f, 0.f);
            ushort4 u;
            u.x = f2bf(v.x); u.y = f2bf(v.y); u.z = f2bf(v.z); u.w = f2bf(v.w);
            *(ushort4*)&xs[r * 72 + q * 4] = u;
        }
        #pragma unroll
        for (int t = 0; t < 8; ++t) {
            int id = t * 512 + tid;
            int r = id >> 4, q = id & 15;
            float4 v = *(const float4*)&W[((size_t)e * C + col0 + r) * D + k0 + q * 4];
            ushort4 u;
            u.x = f2bf(v.x); u.y = f2bf(v.y); u.z = f2bf(v.z); u.w = f2bf(v.w);
            *(ushort4*)&wsh[r * 72 + q * 4] = u;
        }
        __syncthreads();
        #pragma unroll
        for (int ks = 0; ks < 2; ++ks) {
            s16x8 a[4], bfr[4];
            #pragma unroll
            for (int m = 0; m < 4; ++m)
                a[m] = *(const s16x8*)&xs[(wr * 64 + m * 16 + l15) * 72 + ks * 32 + l16 * 8];
            #pragma unroll
            for (int n = 0; n < 4; ++n)
                bfr[n] = *(const s16x8*)&wsh[(wc * 64 + n * 16 + l15) * 72 + ks * 32 + l16 * 8];
            #pragma unroll
            for (int m = 0; m < 4; ++m)
                #pragma unroll
                for (int n = 0; n < 4; ++n)
                    acc[m][n] = __builtin_amdgcn_mfma_f32_16x16x32_bf16(
                        a[m], bfr[n], acc[m][n], 0, 0, 0);
        }
        __syncthreads();
    }

    int kk = kp[0]; kk = kk < 1 ? 1 : (kk > KMAX ? KMAX : kk);
    float invk = 1.0f / (float)kk;
    #pragma unroll
    for (int m = 0; m < 4; ++m) {
        int rbase = wr * 64 + m * 16 + l16 * 4;
        #pragma unroll
        for (int n = 0; n < 4; ++n) {
            int col = col0 + wc * 64 + n * 16 + l15;
            float bv = bias[(size_t)e * C + col];
            #pragma unroll
            for (int r = 0; r < 4; ++r) {
                int rl = rbase + r;
                if (rl < nt)
                    atomicAdd(&out[(size_t)toks[rl] * C + col],
                              invk * (acc[m][n][r] + bv));
            }
        }
    }
}

// ---------------------------------------------------------------------------
extern "C" void kernel_launch(void* const* d_in, const int* in_sizes, int n_in,
                              void* d_out, int out_size, void* d_ws, size_t ws_size,
                              hipStream_t stream) {
    const float* x     = (const float*)d_in[0];
    const float* ef    = (const float*)d_in[1];
    const float* trust = (const float*)d_in[2];
    const float* stale = (const float*)d_in[3];
    const float* W     = (const float*)d_in[4];
    const float* b     = (const float*)d_in[5];
    const int*   kp    = (const int*)d_in[6];

    int E = in_sizes[2];            // 32
    int D = in_sizes[1] / E;        // 1024
    int B = in_sizes[0] / D;        // 8192
    int C = in_sizes[5] / E;        // 256
    float* out = (float*)d_out;

    // workspace layout
    char* ws = (char*)d_ws;
    double* efn   = (double*)ws;                       // 256 B
    int*    counts= (int*)(ws + 256);                  // 32*CSTRIDE*4 = 8 KB
    size_t off_offs = 256 + 32 * CSTRIDE * 4;
    int*    offs  = (int*)(ws + off_offs);             // 256 B
    size_t off_sel = off_offs + 256;
    int*    sel   = (int*)(ws + off_sel);              // B*KMAX*4
    size_t off_lists = off_sel + (size_t)B * KMAX * 4;
    int*    lists = (int*)(ws + off_lists);            // E*B*4
    size_t off_xbf = off_lists + (size_t)E * B * 4;
    off_xbf = (off_xbf + 255) & ~(size_t)255;
    ushort* xbf = (ushort*)(ws + off_xbf);             // B*D*2
    size_t off_wbf = off_xbf + (size_t)B * D * 2;
    ushort* wbf = (ushort*)(ws + off_wbf);             // E*C*D*2
    size_t off_part = off_wbf + (size_t)E * C * D * 2;
    off_part = (off_part + 255) & ~(size_t)255;
    ushort* part = (ushort*)(ws + off_part);           // B*KMAX*C*2 bf16 slots
    size_t need_mid  = off_part;
    size_t need_full = off_part + (size_t)B * KMAX * C * 2;

    bool fullPath = ws_size >= need_mid;
    int usePart = (fullPath && ws_size >= need_full) ? 1 : 0;

    if (!usePart)
        hipMemsetAsync(d_out, 0, (size_t)out_size * sizeof(float), stream);

    k_efnorm<<<E, 64, 0, stream>>>(ef, D, efn, counts);  // also zeroes counts

    if (fullPath) {
        k_scores3<<<B / 16, 256, 0, stream>>>(x, ef, trust, stale, efn,
                                              kp, D, B, xbf, counts, lists, sel);
        int perExpF4 = (C * D) / 4;
        dim3 wgrid((perExpF4 + 1023) / 1024, E);
        k_prep_w<<<wgrid, 256, 0, stream>>>(W, counts, perExpF4, wbf, offs);
        dim3 grid((B + 127) / 128, C / 128, E);
        k_moe3<<<grid, 512, 0, stream>>>(xbf, wbf, b, lists, counts, offs, kp,
                                         B, C, D, usePart, part, out);
        if (usePart)
            k_combine<<<B / 4, 256, 0, stream>>>(part, sel, offs, kp, C, out);
    } else {
        k_scores_legacy<<<B / 32, 256, 0, stream>>>(x, ef, trust, stale, efn,
                                                    kp, D, B, counts, lists);
        dim3 grid((B + 127) / 128, C / 256, E);
        k_moe_f32<<<grid, 512, 0, stream>>>(x, W, b, lists, counts, kp,
                                            B, C, D, out);
    }
}

// Round 16
// 81.973 us; speedup vs baseline: 1.1413x; 1.0256x over previous
//
#include <hip/hip_runtime.h>
#include <math.h>

#define KMAX 8
#define CSTRIDE 64   // ints between expert counters = 256 B -> distinct cache lines

typedef short s16x8 __attribute__((ext_vector_type(8)));
typedef float f32x4 __attribute__((ext_vector_type(4)));

__device__ inline ushort f2bf(float f) {
    union { float f; unsigned u; } v; v.f = f;
    unsigned r = v.u + 0x7fffu + ((v.u >> 16) & 1u);   // RNE
    return (ushort)(r >> 16);
}
__device__ inline float bf2f(ushort b) {
    union { unsigned u; float f; } v; v.u = ((unsigned)b) << 16; return v.f;
}

__device__ inline void gload_lds16(const void* g, void* l) {
    __builtin_amdgcn_global_load_lds(
        (const __attribute__((address_space(1))) unsigned int*)g,
        (__attribute__((address_space(3))) unsigned int*)l, 16, 0, 0);
}

// ---------------------------------------------------------------------------
// K0: per-expert feature norms in double + counts zeroing.  E blocks x 64.
// ---------------------------------------------------------------------------
__global__ void k_efnorm(const float* __restrict__ ef, int D,
                         double* __restrict__ efn, int* __restrict__ counts) {
    int e = blockIdx.x;
    int lane = threadIdx.x;  // 64
    if (lane == 0) counts[e * CSTRIDE] = 0;
    double s = 0.0;
    for (int i = lane; i < D; i += 64) {
        double v = (double)ef[(size_t)e * D + i];
        s = fma(v, v, s);
    }
    #pragma unroll
    for (int off = 32; off > 0; off >>= 1) s += __shfl_xor(s, off);
    if (lane == 0) efn[e] = sqrt(s);
}

// ---------------------------------------------------------------------------
// K2: W -> bf16, GATED on counts[e] > 0; block (0,0) also computes offs[].
// ---------------------------------------------------------------------------
__global__ __launch_bounds__(256) void k_prep_w(
    const float* __restrict__ W, const int* __restrict__ counts,
    int perExpF4, ushort* __restrict__ wbf, int* __restrict__ offs) {
    int e = blockIdx.y;
    if (blockIdx.x == 0 && e == 0 && threadIdx.x == 0) {
        int s = 0;
        for (int e2 = 0; e2 < 32; ++e2) { offs[e2] = s; s += counts[e2 * CSTRIDE]; }
    }
    if (counts[e * CSTRIDE] == 0) return;
    size_t base = (size_t)e * perExpF4;
    #pragma unroll
    for (int j = 0; j < 4; ++j) {
        int idx = (blockIdx.x * 4 + j) * 256 + threadIdx.x;
        if (idx < perExpF4) {
            float4 v = *(const float4*)&W[(base + idx) * 4];
            ushort4 u;
            u.x = f2bf(v.x); u.y = f2bf(v.y); u.z = f2bf(v.z); u.w = f2bf(v.w);
            *(ushort4*)&wbf[(base + idx) * 4] = u;
        }
    }
}

// ---------------------------------------------------------------------------
// K3a: D-SPLIT partial scores.  grid = (B/16)*2 blocks, 256 threads.
// Block (g = bid>>1, h = bid&1) handles 16 tokens x D/2 (half h): identical
// chunk-64 staging + T14 prefetch as the round-12 kernel, f32 chains + f64
// accumulation (same error class; f64 half-sum addition adds ~1e-16, far
// below the proven-tolerated f32-chain noise).  Writes coalesced partial
// dots pacc[(h*32+e)*B + t], partial ||x||^2 paxx[h*B + t], and its half of
// the xbf mirror.  No top-k tail -> 2x grid = 4 blocks/CU (scores3 was
// grid-limited at 2/CU, Occupancy ~17%).
// ---------------------------------------------------------------------------
__global__ __launch_bounds__(256) void k_scores3a(
    const float* __restrict__ x, const float* __restrict__ ef,
    int D, int B, ushort* __restrict__ xbf,
    double* __restrict__ pacc, double* __restrict__ paxx)
{
    __shared__ float xs[16 * 64];           // 4 KB
    __shared__ float efs[32 * 64];          // 8 KB

    int tid = threadIdx.x;
    int tp = tid >> 4, eg = tid & 15;
    int g = blockIdx.x >> 1, h = blockIdx.x & 1;
    int tb = g * 16;
    int kbase = h * (D >> 1);
    int nch = D >> 7;                       // (D/2)/64

    int rx = tid >> 4, qx = tid & 15;
    int re0 = tid >> 4, re1 = 16 + (tid >> 4);
    int qe = tid & 15;

    float4 vx  = *(const float4*)&x[(size_t)(tb + rx) * D + kbase + qx * 4];
    float4 ve0 = *(const float4*)&ef[(size_t)re0 * D + kbase + qe * 4];
    float4 ve1 = *(const float4*)&ef[(size_t)re1 * D + kbase + qe * 4];

    double acc0 = 0.0, acc1 = 0.0, axx = 0.0;

    for (int ch = 0; ch < nch; ++ch) {
        int k0 = kbase + ch * 64;
        *(float4*)&xs[rx * 64 + ((qx ^ rx) << 2)] = vx;
        {
            ushort4 u;
            u.x = f2bf(vx.x); u.y = f2bf(vx.y); u.z = f2bf(vx.z); u.w = f2bf(vx.w);
            *(ushort4*)&xbf[(size_t)(tb + rx) * D + k0 + qx * 4] = u;
        }
        *(float4*)&efs[re0 * 64 + ((qe ^ (re0 & 15)) << 2)] = ve0;
        *(float4*)&efs[re1 * 64 + ((qe ^ (re1 & 15)) << 2)] = ve1;
        __syncthreads();

        if (ch + 1 < nch) {
            int k1 = kbase + (ch + 1) * 64;
            vx  = *(const float4*)&x[(size_t)(tb + rx) * D + k1 + qx * 4];
            ve0 = *(const float4*)&ef[(size_t)re0 * D + k1 + qe * 4];
            ve1 = *(const float4*)&ef[(size_t)re1 * D + k1 + qe * 4];
        }

        float a0 = 0.f, a1 = 0.f, ax = 0.f;
        #pragma unroll
        for (int q = 0; q < 16; ++q) {
            float4 xv = *(const float4*)&xs[tp * 64 + ((q ^ tp) << 2)];
            float4 e0 = *(const float4*)&efs[eg * 64 + ((q ^ eg) << 2)];
            float4 e1 = *(const float4*)&efs[(eg + 16) * 64 + ((q ^ eg) << 2)];
            a0 = fmaf(xv.x, e0.x, a0); a0 = fmaf(xv.y, e0.y, a0);
            a0 = fmaf(xv.z, e0.z, a0); a0 = fmaf(xv.w, e0.w, a0);
            a1 = fmaf(xv.x, e1.x, a1); a1 = fmaf(xv.y, e1.y, a1);
            a1 = fmaf(xv.z, e1.z, a1); a1 = fmaf(xv.w, e1.w, a1);
            ax = fmaf(xv.x, xv.x, ax); ax = fmaf(xv.y, xv.y, ax);
            ax = fmaf(xv.z, xv.z, ax); ax = fmaf(xv.w, xv.w, ax);
        }
        __syncthreads();
        acc0 += (double)a0; acc1 += (double)a1; axx += (double)ax;
    }

    int tt = tb + tp;
    pacc[(size_t)(h * 32 + eg) * B + tt] = acc0;
    pacc[(size_t)(h * 32 + eg + 16) * B + tt] = acc1;
    if (eg == 0) paxx[(size_t)h * B + tt] = axx;
}

// ---------------------------------------------------------------------------
// K3b: combine halves + compose scores + top-k + scatter + sel map.
// grid = B/128 blocks, 256 threads (thread (tk=tid&127, eh=tid>>7) composes
// 16 experts for token tk).  Reads 4 MB L2-resident partials (coalesced).
// Top-k: strict > scan, lowest-index tie-break == jax.lax.top_k selected
// set.  Hierarchical scatter (round-4 fix).
// ---------------------------------------------------------------------------
__global__ __launch_bounds__(256) void k_scores3b(
    const float* __restrict__ trust, const float* __restrict__ stale,
    const double* __restrict__ efn, const double* __restrict__ pacc,
    const double* __restrict__ paxx, const int* __restrict__ kp,
    int B, int* __restrict__ counts, int* __restrict__ lists,
    int* __restrict__ sel)
{
    __shared__ double sc[128 * 33];         // 33.8 KB
    __shared__ int bcnt[32];
    __shared__ int bbase[32];
    __shared__ unsigned char selb[128 * KMAX];
    __shared__ unsigned char lposb[128 * KMAX];

    int tid = threadIdx.x;
    int tk = tid & 127, eh = tid >> 7;
    int t = blockIdx.x * 128 + tk;

    if (tid < 32) bcnt[tid] = 0;

    double axx = paxx[t] + paxx[(size_t)B + t];
    double xn = fmax(sqrt(axx), 1e-8);
    #pragma unroll
    for (int j = 0; j < 16; ++j) {
        int e = eh * 16 + j;
        double dot = pacc[(size_t)e * B + t] + pacc[(size_t)(32 + e) * B + t];
        double en = fmax(efn[e], 1e-8);
        sc[tk * 33 + e] = 0.4 * (double)trust[e]
            + 0.2 * (dot / (xn * en) + 1.0)
            + 0.2 * fmax(0.0, 1.0 - (double)stale[e]);
    }
    __syncthreads();

    int kk = kp[0]; kk = kk < 1 ? 1 : (kk > KMAX ? KMAX : kk);

    if (tid < 128) {
        unsigned mask = 0;
        for (int p = 0; p < kk; ++p) {
            double bv = -1e300; int be = 0;
            #pragma unroll
            for (int e = 0; e < 32; ++e) {
                double v = sc[tid * 33 + e];
                if (!((mask >> e) & 1u) && v > bv) { bv = v; be = e; }
            }
            mask |= 1u << be;
            selb[tid * KMAX + p] = (unsigned char)be;
            lposb[tid * KMAX + p] = (unsigned char)atomicAdd(&bcnt[be], 1);
        }
    }
    __syncthreads();
    if (tid < 32) {
        int c = bcnt[tid];
        bbase[tid] = c ? atomicAdd(&counts[tid * CSTRIDE], c) : 0;
    }
    __syncthreads();
    if (tid < 128) {
        int tt = blockIdx.x * 128 + tid;
        for (int p = 0; p < kk; ++p) {
            int e = selb[tid * KMAX + p];
            int pos = bbase[e] + lposb[tid * KMAX + p];
            lists[(size_t)e * B + pos] = tt;
            sel[(size_t)tt * KMAX + p] = (e << 24) | pos;
        }
    }
}

// ---------------------------------------------------------------------------
// K4 v3: grouped expert GEMM (round-10/12 proven — BM=128, BN=128,
// 512 threads = 8 waves, wave tile 32x64, single-buffer 2-barrier K-loop,
// XOR swizzle both sides -> 0 conflicts, bf16 part stores / atomic fallback).
// ---------------------------------------------------------------------------
__global__ __launch_bounds__(512) void k_moe3(
    const ushort* __restrict__ xbf, const ushort* __restrict__ wbf,
    const float* __restrict__ bias, const int* __restrict__ lists,
    const int* __restrict__ counts, const int* __restrict__ offs,
    const int* __restrict__ kp, int B, int C, int D,
    int usePart, ushort* __restrict__ part, float* __restrict__ out)
{
    int e = blockIdx.z;
    int cnt = counts[e * CSTRIDE];
    int row0 = blockIdx.x * 128;
    if (row0 >= cnt) return;            // uniform: safe before barriers
    int col0 = blockIdx.y * 128;
    int nt = min(128, cnt - row0);

    __shared__ ushort xs[128 * 64];     // 16 KB
    __shared__ ushort wsh[128 * 64];    // 16 KB
    __shared__ int toks[128];

    int tid = threadIdx.x;
    if (tid < 128) toks[tid] = (tid < nt) ? lists[(size_t)e * B + row0 + tid] : 0;
    __syncthreads();

    int lane = tid & 63, wid = tid >> 6;
    int wr = wid >> 1, wc = wid & 1;    // wave tile: rows wr*32, cols wc*64
    int l15 = lane & 15, l16 = lane >> 4;

    f32x4 acc[2][4];
    #pragma unroll
    for (int m = 0; m < 2; ++m)
        #pragma unroll
        for (int n = 0; n < 4; ++n) acc[m][n] = (f32x4){0.f, 0.f, 0.f, 0.f};

    int nch = D / 64;
    for (int ch = 0; ch < nch; ++ch) {
        int k0 = ch * 64;
        #pragma unroll
        for (int t = 0; t < 2; ++t) {
            int id = t * 512 + tid;
            int r = id >> 3, seg = id & 7;
            int ssw = (seg ^ (r & 7)) << 3;
            gload_lds16(&xbf[(size_t)toks[r] * D + k0 + ssw],
                        (char*)xs + (size_t)(t * 512 + wid * 64) * 16);
        }
        #pragma unroll
        for (int t = 0; t < 2; ++t) {
            int id = t * 512 + tid;
            int r = id >> 3, seg = id & 7;
            int ssw = (seg ^ (r & 7)) << 3;
            gload_lds16(&wbf[((size_t)e * C + col0 + r) * D + k0 + ssw],
                        (char*)wsh + (size_t)(t * 512 + wid * 64) * 16);
        }
        __syncthreads();
        #pragma unroll
        for (int ks = 0; ks < 2; ++ks) {
            s16x8 a[2], bfr[4];
            int sbase = ks * 4 + l16;
            #pragma unroll
            for (int m = 0; m < 2; ++m) {
                int r = wr * 32 + m * 16 + l15;
                a[m] = *(const s16x8*)&xs[r * 64 + ((sbase ^ (l15 & 7)) << 3)];
            }
            #pragma unroll
            for (int n = 0; n < 4; ++n) {
                int r = wc * 64 + n * 16 + l15;
                bfr[n] = *(const s16x8*)&wsh[r * 64 + ((sbase ^ (l15 & 7)) << 3)];
            }
            #pragma unroll
            for (int m = 0; m < 2; ++m)
                #pragma unroll
                for (int n = 0; n < 4; ++n)
                    acc[m][n] = __builtin_amdgcn_mfma_f32_16x16x32_bf16(
                        a[m], bfr[n], acc[m][n], 0, 0, 0);
        }
        __syncthreads();
    }

    int kk = kp[0]; kk = kk < 1 ? 1 : (kk > KMAX ? KMAX : kk);
    // C/D layout (m89): col = lane&15, row = (lane>>4)*4 + reg
    if (usePart) {
        int slotBase = offs[e] + row0;
        #pragma unroll
        for (int m = 0; m < 2; ++m) {
            int rbase = wr * 32 + m * 16 + l16 * 4;
            #pragma unroll
            for (int n = 0; n < 4; ++n) {
                int col = col0 + wc * 64 + n * 16 + l15;
                float bv = bias[(size_t)e * C + col];
                #pragma unroll
                for (int r = 0; r < 4; ++r) {
                    int rl = rbase + r;
                    if (rl < nt)
                        part[(size_t)(slotBase + rl) * C + col] =
                            f2bf(acc[m][n][r] + bv);
                }
            }
        }
    } else {
        float invk = 1.0f / (float)kk;
        #pragma unroll
        for (int m = 0; m < 2; ++m) {
            int rbase = wr * 32 + m * 16 + l16 * 4;
            #pragma unroll
            for (int n = 0; n < 4; ++n) {
                int col = col0 + wc * 64 + n * 16 + l15;
                float bv = bias[(size_t)e * C + col];
                #pragma unroll
                for (int r = 0; r < 4; ++r) {
                    int rl = rbase + r;
                    if (rl < nt)
                        atomicAdd(&out[(size_t)toks[rl] * C + col],
                                  invk * (acc[m][n][r] + bv));
                }
            }
        }
    }
}

// ---------------------------------------------------------------------------
// K5: combine — out[t][c] = (1/k) * sum_p bf2f(part[slot_p*C + c]).
// ---------------------------------------------------------------------------
__global__ __launch_bounds__(256) void k_combine(
    const ushort* __restrict__ part, const int* __restrict__ sel,
    const int* __restrict__ offs, const int* __restrict__ kp,
    int C, float* __restrict__ out)
{
    int kk = kp[0]; kk = kk < 1 ? 1 : (kk > KMAX ? KMAX : kk);
    float invk = 1.0f / (float)kk;
    int sub = threadIdx.x >> 6, lane = threadIdx.x & 63;
    int t = blockIdx.x * 4 + sub;
    for (int c = lane * 4; c < C; c += 256) {
        float s0 = 0.f, s1 = 0.f, s2 = 0.f, s3 = 0.f;
        for (int p = 0; p < kk; ++p) {
            int sv = sel[(size_t)t * KMAX + p];
            int slot = offs[sv >> 24] + (sv & 0xFFFFFF);
            ushort4 u = *(const ushort4*)&part[(size_t)slot * C + c];
            s0 += bf2f(u.x); s1 += bf2f(u.y); s2 += bf2f(u.z); s3 += bf2f(u.w);
        }
        float4 o = make_float4(invk * s0, invk * s1, invk * s2, invk * s3);
        *(float4*)&out[(size_t)t * C + c] = o;
    }
}

// ===========================================================================
// Legacy fallback — only if ws_size is too small for the bf16 mirrors.
// ===========================================================================
__global__ __launch_bounds__(256) void k_scores_legacy(
    const float* __restrict__ x, const float* __restrict__ ef,
    const float* __restrict__ trust, const float* __restrict__ stale,
    const double* __restrict__ efn, const int* __restrict__ kp,
    int D, int B, int* __restrict__ counts, int* __restrict__ lists)
{
    __shared__ float xs[32][72];
    __shared__ float efs[32][72];
    __shared__ double sc[32][33];

    int tid = threadIdx.x;
    int tl = tid >> 3, eg = tid & 7;
    int tb = blockIdx.x * 32;

    double acc[4] = {0, 0, 0, 0};
    double axx = 0.0;
    int nch = D / 64;

    for (int ch = 0; ch < nch; ++ch) {
        #pragma unroll
        for (int t = 0; t < 2; ++t) {
            int id = t * 256 + tid;
            int r = id >> 4, q = id & 15;
            float4 v = *(const float4*)&x[(size_t)(tb + r) * D + ch * 64 + q * 4];
            *(float4*)&xs[r][q * 4] = v;
            float4 w = *(const float4*)&ef[(size_t)r * D + ch * 64 + q * 4];
            *(float4*)&efs[r][q * 4] = w;
        }
        __syncthreads();
        #pragma unroll 4
        for (int q = 0; q < 16; ++q) {
            float4 xv = *(const float4*)&xs[tl][q * 4];
            double x0 = xv.x, x1 = xv.y, x2 = xv.z, x3 = xv.w;
            axx = fma(x0, x0, fma(x1, x1, fma(x2, x2, fma(x3, x3, axx))));
            #pragma unroll
            for (int j = 0; j < 4; ++j) {
                float4 ev = *(const float4*)&efs[eg + 8 * j][q * 4];
                acc[j] = fma(x0, (double)ev.x, acc[j]);
                acc[j] = fma(x1, (double)ev.y, acc[j]);
                acc[j] = fma(x2, (double)ev.z, acc[j]);
                acc[j] = fma(x3, (double)ev.w, acc[j]);
            }
        }
        __syncthreads();
    }

    double xn = fmax(sqrt(axx), 1e-8);
    #pragma unroll
    for (int j = 0; j < 4; ++j) {
        int e = eg + 8 * j;
        double en = fmax(efn[e], 1e-8);
        double cosv = acc[j] / (xn * en);
        sc[tl][e] = 0.4 * (double)trust[e] + 0.2 * (cosv + 1.0)
                  + 0.2 * fmax(0.0, 1.0 - (double)stale[e]);
    }
    __syncthreads();

    if (tid < 32) {
        int kk = kp[0]; kk = kk < 1 ? 1 : (kk > KMAX ? KMAX : kk);
        unsigned mask = 0;
        int t = tb + tid;
        for (int p = 0; p < kk; ++p) {
            double bv = -1e300; int be = 0;
            #pragma unroll
            for (int e = 0; e < 32; ++e) {
                double v = sc[tid][e];
                if (!((mask >> e) & 1u) && v > bv) { bv = v; be = e; }
            }
            mask |= 1u << be;
            int pos = atomicAdd(&counts[be * CSTRIDE], 1);
            lists[(size_t)be * B + pos] = t;
        }
    }
}

__global__ __launch_bounds__(512) void k_moe_f32(
    const float* __restrict__ x, const float* __restrict__ W,
    const float* __restrict__ bias, const int* __restrict__ lists,
    const int* __restrict__ counts, const int* __restrict__ kp,
    int B, int C, int D, float* __restrict__ out)
{
    int e = blockIdx.z;
    int cnt = counts[e * CSTRIDE];
    int row0 = blockIdx.x * 128;
    if (row0 >= cnt) return;
    int col0 = blockIdx.y * 256;
    int nt = min(128, cnt - row0);

    __shared__ ushort xs[128 * 72];
    __shared__ ushort wsh[256 * 72];
    __shared__ int toks[128];

    int tid = threadIdx.x;
    if (tid < 128) toks[tid] = (tid < nt) ? lists[(size_t)e * B + row0 + tid] : 0;
    __syncthreads();

    int lane = tid & 63, wid = tid >> 6;
    int wr = wid >> 2, wc = wid & 3;
    int l15 = lane & 15, l16 = lane >> 4;

    f32x4 acc[4][4];
    #pragma unroll
    for (int m = 0; m < 4; ++m)
        #pragma unroll
        for (int n = 0; n < 4; ++n) acc[m][n] = (f32x4){0.f, 0.f, 0.f, 0.f};

    int nch = D / 64;
    for (int ch = 0; ch < nch; ++ch) {
        int k0 = ch * 64;
        #pragma unroll
        for (int t = 0; t < 4; ++t) {
            int id = t * 512 + tid;
            int r = id >> 4, q = id & 15;
            float4 v = (r < nt)
                ? *(const float4*)&x[(size_t)toks[r] * D + k0 + q * 4]
                : make_float4(0.f, 0.f, 0.f, 0.f);
            ushort4 u;
            u.x = f2bf(v.x); u.y = f2bf(v.y); u.z = f2bf(v.z); u.w = f2bf(v.w);
            *(ushort4*)&xs[r * 72 + q * 4] = u;
        }
        #pragma unroll
        for (int t = 0; t < 8; ++t) {
            int id = t * 512 + tid;
            int r = id >> 4, q = id & 15;
            float4 v = *(const float4*)&W[((size_t)e * C + col0 + r) * D + k0 + q * 4];
            ushort4 u;
            u.x = f2bf(v.x); u.y = f2bf(v.y); u.z = f2bf(v.z); u.w = f2bf(v.w);
            *(ushort4*)&wsh[r * 72 + q * 4] = u;
        }
        __syncthreads();
        #pragma unroll
        for (int ks = 0; ks < 2; ++ks) {
            s16x8 a[4], bfr[4];
            #pragma unroll
            for (int m = 0; m < 4; ++m)
                a[m] = *(const s16x8*)&xs[(wr * 64 + m * 16 + l15) * 72 + ks * 32 + l16 * 8];
            #pragma unroll
            for (int n = 0; n < 4; ++n)
                bfr[n] = *(const s16x8*)&wsh[(wc * 64 + n * 16 + l15) * 72 + ks * 32 + l16 * 8];
            #pragma unroll
            for (int m = 0; m < 4; ++m)
                #pragma unroll
                for (int n = 0; n < 4; ++n)
                    acc[m][n] = __builtin_amdgcn_mfma_f32_16x16x32_bf16(
                        a[m], bfr[n], acc[m][n], 0, 0, 0);
        }
        __syncthreads();
    }

    int kk = kp[0]; kk = kk < 1 ? 1 : (kk > KMAX ? KMAX : kk);
    float invk = 1.0f / (float)kk;
    #pragma unroll
    for (int m = 0; m < 4; ++m) {
        int rbase = wr * 64 + m * 16 + l16 * 4;
        #pragma unroll
        for (int n = 0; n < 4; ++n) {
            int col = col0 + wc * 64 + n * 16 + l15;
            float bv = bias[(size_t)e * C + col];
            #pragma unroll
            for (int r = 0; r < 4; ++r) {
                int rl = rbase + r;
                if (rl < nt)
                    atomicAdd(&out[(size_t)toks[rl] * C + col],
                              invk * (acc[m][n][r] + bv));
            }
        }
    }
}

// ---------------------------------------------------------------------------
extern "C" void kernel_launch(void* const* d_in, const int* in_sizes, int n_in,
                              void* d_out, int out_size, void* d_ws, size_t ws_size,
                              hipStream_t stream) {
    const float* x     = (const float*)d_in[0];
    const float* ef    = (const float*)d_in[1];
    const float* trust = (const float*)d_in[2];
    const float* stale = (const float*)d_in[3];
    const float* W     = (const float*)d_in[4];
    const float* b     = (const float*)d_in[5];
    const int*   kp    = (const int*)d_in[6];

    int E = in_sizes[2];            // 32
    int D = in_sizes[1] / E;        // 1024
    int B = in_sizes[0] / D;        // 8192
    int C = in_sizes[5] / E;        // 256
    float* out = (float*)d_out;

    // workspace layout
    char* ws = (char*)d_ws;
    double* efn   = (double*)ws;                       // 256 B
    int*    counts= (int*)(ws + 256);                  // 32*CSTRIDE*4 = 8 KB
    size_t off_offs = 256 + 32 * CSTRIDE * 4;
    int*    offs  = (int*)(ws + off_offs);             // 256 B
    size_t off_sel = off_offs + 256;
    int*    sel   = (int*)(ws + off_sel);              // B*KMAX*4
    size_t off_lists = off_sel + (size_t)B * KMAX * 4;
    int*    lists = (int*)(ws + off_lists);            // E*B*4
    size_t off_pacc = off_lists + (size_t)E * B * 4;
    off_pacc = (off_pacc + 255) & ~(size_t)255;
    double* pacc  = (double*)(ws + off_pacc);          // 64*B*8 = 4 MB
    size_t off_paxx = off_pacc + (size_t)64 * B * 8;
    double* paxx  = (double*)(ws + off_paxx);          // 2*B*8
    size_t off_xbf = off_paxx + (size_t)2 * B * 8;
    off_xbf = (off_xbf + 255) & ~(size_t)255;
    ushort* xbf = (ushort*)(ws + off_xbf);             // B*D*2
    size_t off_wbf = off_xbf + (size_t)B * D * 2;
    ushort* wbf = (ushort*)(ws + off_wbf);             // E*C*D*2
    size_t off_part = off_wbf + (size_t)E * C * D * 2;
    off_part = (off_part + 255) & ~(size_t)255;
    ushort* part = (ushort*)(ws + off_part);           // B*KMAX*C*2 bf16 slots
    size_t need_mid  = off_part;
    size_t need_full = off_part + (size_t)B * KMAX * C * 2;

    bool fullPath = ws_size >= need_mid;
    int usePart = (fullPath && ws_size >= need_full) ? 1 : 0;

    if (!usePart)
        hipMemsetAsync(d_out, 0, (size_t)out_size * sizeof(float), stream);

    k_efnorm<<<E, 64, 0, stream>>>(ef, D, efn, counts);  // also zeroes counts

    if (fullPath) {
        k_scores3a<<<(B / 16) * 2, 256, 0, stream>>>(x, ef, D, B, xbf,
                                                     pacc, paxx);
        k_scores3b<<<B / 128, 256, 0, stream>>>(trust, stale, efn, pacc, paxx,
                                                kp, B, counts, lists, sel);
        int perExpF4 = (C * D) / 4;
        dim3 wgrid((perExpF4 + 1023) / 1024, E);
        k_prep_w<<<wgrid, 256, 0, stream>>>(W, counts, perExpF4, wbf, offs);
        dim3 grid((B + 127) / 128, C / 128, E);
        k_moe3<<<grid, 512, 0, stream>>>(xbf, wbf, b, lists, counts, offs, kp,
                                         B, C, D, usePart, part, out);
        if (usePart)
            k_combine<<<B / 4, 256, 0, stream>>>(part, sel, offs, kp, C, out);
    } else {
        k_scores_legacy<<<B / 32, 256, 0, stream>>>(x, ef, trust, stale, efn,
                                                    kp, D, B, counts, lists);
        dim3 grid((B + 127) / 128, C / 256, E);
        k_moe_f32<<<grid, 512, 0, stream>>>(x, W, b, lists, counts, kp,
                                            B, C, D, out);
    }
}

// Round 17
// 78.375 us; speedup vs baseline: 1.1936x; 1.0459x over previous
//
#include <hip/hip_runtime.h>
#include <math.h>

#define KMAX 8
#define CSTRIDE 64   // ints between expert counters = 256 B -> distinct cache lines

typedef short s16x8 __attribute__((ext_vector_type(8)));
typedef float f32x4 __attribute__((ext_vector_type(4)));

__device__ inline ushort f2bf(float f) {
    union { float f; unsigned u; } v; v.f = f;
    unsigned r = v.u + 0x7fffu + ((v.u >> 16) & 1u);   // RNE
    return (ushort)(r >> 16);
}
__device__ inline float bf2f(ushort b) {
    union { unsigned u; float f; } v; v.u = ((unsigned)b) << 16; return v.f;
}

__device__ inline void gload_lds16(const void* g, void* l) {
    __builtin_amdgcn_global_load_lds(
        (const __attribute__((address_space(1))) unsigned int*)g,
        (__attribute__((address_space(3))) unsigned int*)l, 16, 0, 0);
}

// ---------------------------------------------------------------------------
// K0 (legacy path only): per-expert feature norms + counts zeroing.
// ---------------------------------------------------------------------------
__global__ void k_efnorm(const float* __restrict__ ef, int D,
                         double* __restrict__ efn, int* __restrict__ counts) {
    int e = blockIdx.x;
    int lane = threadIdx.x;  // 64
    if (lane == 0) counts[e * CSTRIDE] = 0;
    double s = 0.0;
    for (int i = lane; i < D; i += 64) {
        double v = (double)ef[(size_t)e * D + i];
        s = fma(v, v, s);
    }
    #pragma unroll
    for (int off = 32; off > 0; off >>= 1) s += __shfl_xor(s, off);
    if (lane == 0) efn[e] = sqrt(s);
}

// ---------------------------------------------------------------------------
// K2: W -> bf16, GATED on counts[e] > 0; block (0,0) also computes offs[].
// ---------------------------------------------------------------------------
__global__ __launch_bounds__(256) void k_prep_w(
    const float* __restrict__ W, const int* __restrict__ counts,
    int perExpF4, ushort* __restrict__ wbf, int* __restrict__ offs) {
    int e = blockIdx.y;
    if (blockIdx.x == 0 && e == 0 && threadIdx.x == 0) {
        int s = 0;
        for (int e2 = 0; e2 < 32; ++e2) { offs[e2] = s; s += counts[e2 * CSTRIDE]; }
    }
    if (counts[e * CSTRIDE] == 0) return;
    size_t base = (size_t)e * perExpF4;
    #pragma unroll
    for (int j = 0; j < 4; ++j) {
        int idx = (blockIdx.x * 4 + j) * 256 + threadIdx.x;
        if (idx < perExpF4) {
            float4 v = *(const float4*)&W[(base + idx) * 4];
            ushort4 u;
            u.x = f2bf(v.x); u.y = f2bf(v.y); u.z = f2bf(v.z); u.w = f2bf(v.w);
            *(ushort4*)&wbf[(base + idx) * 4] = u;
        }
    }
}

// ---------------------------------------------------------------------------
// K3a: D-SPLIT x4 partial scores + fused efnorm blocks.
// Blocks [0, 4*nSB): (g = bid>>2, h = bid&3) handles 16 tokens x D/4:
// identical chunk-64 staging + T14 prefetch (r12-proven), f32 chains + f64
// accumulation (256-elem chains = LESS error than the proven 512).  Writes
// coalesced pacc[(h*32+e)*B + t], paxx[h*B + t], and its D-quarter of xbf.
// 2048 blocks ~ 8/CU (occupancy lever: won in r6 and r16).
// Blocks [4*nSB, 4*nSB+E): per-expert ef-norm (f64, 256-thread reduce) +
// counts zeroing — folded here to drop the k_efnorm graph node; 3b (the only
// consumer) launches after this whole grid completes, so it's dependency-safe.
// ---------------------------------------------------------------------------
__global__ __launch_bounds__(256) void k_scores3a(
    const float* __restrict__ x, const float* __restrict__ ef,
    int D, int B, int nSB4, ushort* __restrict__ xbf,
    double* __restrict__ pacc, double* __restrict__ paxx,
    double* __restrict__ efn, int* __restrict__ counts)
{
    __shared__ float xs[16 * 64];           // 4 KB
    __shared__ float efs[32 * 64];          // 8 KB
    __shared__ double wsum[4];

    int tid = threadIdx.x;

    // ---------------- efnorm blocks ----------------------------------------
    if ((int)blockIdx.x >= nSB4) {
        int e = blockIdx.x - nSB4;
        if (tid == 0) counts[e * CSTRIDE] = 0;
        double s = 0.0;
        for (int i = tid; i < D; i += 256) {
            double v = (double)ef[(size_t)e * D + i];
            s = fma(v, v, s);
        }
        #pragma unroll
        for (int off = 32; off > 0; off >>= 1) s += __shfl_xor(s, off);
        if ((tid & 63) == 0) wsum[tid >> 6] = s;
        __syncthreads();
        if (tid == 0) efn[e] = sqrt(wsum[0] + wsum[1] + wsum[2] + wsum[3]);
        return;
    }

    // ---------------- partial-scores blocks --------------------------------
    int tp = tid >> 4, eg = tid & 15;
    int g = blockIdx.x >> 2, h = blockIdx.x & 3;
    int tb = g * 16;
    int kbase = h * (D >> 2);
    int nch = D >> 8;                       // (D/4)/64

    int rx = tid >> 4, qx = tid & 15;
    int re0 = tid >> 4, re1 = 16 + (tid >> 4);
    int qe = tid & 15;

    float4 vx  = *(const float4*)&x[(size_t)(tb + rx) * D + kbase + qx * 4];
    float4 ve0 = *(const float4*)&ef[(size_t)re0 * D + kbase + qe * 4];
    float4 ve1 = *(const float4*)&ef[(size_t)re1 * D + kbase + qe * 4];

    double acc0 = 0.0, acc1 = 0.0, axx = 0.0;

    for (int ch = 0; ch < nch; ++ch) {
        int k0 = kbase + ch * 64;
        *(float4*)&xs[rx * 64 + ((qx ^ rx) << 2)] = vx;
        {
            ushort4 u;
            u.x = f2bf(vx.x); u.y = f2bf(vx.y); u.z = f2bf(vx.z); u.w = f2bf(vx.w);
            *(ushort4*)&xbf[(size_t)(tb + rx) * D + k0 + qx * 4] = u;
        }
        *(float4*)&efs[re0 * 64 + ((qe ^ (re0 & 15)) << 2)] = ve0;
        *(float4*)&efs[re1 * 64 + ((qe ^ (re1 & 15)) << 2)] = ve1;
        __syncthreads();

        if (ch + 1 < nch) {
            int k1 = kbase + (ch + 1) * 64;
            vx  = *(const float4*)&x[(size_t)(tb + rx) * D + k1 + qx * 4];
            ve0 = *(const float4*)&ef[(size_t)re0 * D + k1 + qe * 4];
            ve1 = *(const float4*)&ef[(size_t)re1 * D + k1 + qe * 4];
        }

        float a0 = 0.f, a1 = 0.f, ax = 0.f;
        #pragma unroll
        for (int q = 0; q < 16; ++q) {
            float4 xv = *(const float4*)&xs[tp * 64 + ((q ^ tp) << 2)];
            float4 e0 = *(const float4*)&efs[eg * 64 + ((q ^ eg) << 2)];
            float4 e1 = *(const float4*)&efs[(eg + 16) * 64 + ((q ^ eg) << 2)];
            a0 = fmaf(xv.x, e0.x, a0); a0 = fmaf(xv.y, e0.y, a0);
            a0 = fmaf(xv.z, e0.z, a0); a0 = fmaf(xv.w, e0.w, a0);
            a1 = fmaf(xv.x, e1.x, a1); a1 = fmaf(xv.y, e1.y, a1);
            a1 = fmaf(xv.z, e1.z, a1); a1 = fmaf(xv.w, e1.w, a1);
            ax = fmaf(xv.x, xv.x, ax); ax = fmaf(xv.y, xv.y, ax);
            ax = fmaf(xv.z, xv.z, ax); ax = fmaf(xv.w, xv.w, ax);
        }
        __syncthreads();
        acc0 += (double)a0; acc1 += (double)a1; axx += (double)ax;
    }

    int tt = tb + tp;
    pacc[(size_t)(h * 32 + eg) * B + tt] = acc0;
    pacc[(size_t)(h * 32 + eg + 16) * B + tt] = acc1;
    if (eg == 0) paxx[(size_t)h * B + tt] = axx;
}

// ---------------------------------------------------------------------------
// K3b: combine 4 D-quarters + compose scores + top-k + scatter + sel map.
// grid = B/128 blocks, 256 threads (thread (tk=tid&127, eh=tid>>7) composes
// 16 experts for token tk).  Reads 8 MB L2-resident partials (coalesced).
// Top-k: strict > scan, lowest-index tie-break == jax.lax.top_k selected
// set.  Hierarchical scatter (round-4 fix).
// ---------------------------------------------------------------------------
__global__ __launch_bounds__(256) void k_scores3b(
    const float* __restrict__ trust, const float* __restrict__ stale,
    const double* __restrict__ efn, const double* __restrict__ pacc,
    const double* __restrict__ paxx, const int* __restrict__ kp,
    int B, int* __restrict__ counts, int* __restrict__ lists,
    int* __restrict__ sel)
{
    __shared__ double sc[128 * 33];         // 33.8 KB
    __shared__ int bcnt[32];
    __shared__ int bbase[32];
    __shared__ unsigned char selb[128 * KMAX];
    __shared__ unsigned char lposb[128 * KMAX];

    int tid = threadIdx.x;
    int tk = tid & 127, eh = tid >> 7;
    int t = blockIdx.x * 128 + tk;

    if (tid < 32) bcnt[tid] = 0;

    double axx = (paxx[t] + paxx[(size_t)B + t])
               + (paxx[(size_t)2 * B + t] + paxx[(size_t)3 * B + t]);
    double xn = fmax(sqrt(axx), 1e-8);
    #pragma unroll
    for (int j = 0; j < 16; ++j) {
        int e = eh * 16 + j;
        double dot = (pacc[(size_t)e * B + t] + pacc[(size_t)(32 + e) * B + t])
                   + (pacc[(size_t)(64 + e) * B + t] + pacc[(size_t)(96 + e) * B + t]);
        double en = fmax(efn[e], 1e-8);
        sc[tk * 33 + e] = 0.4 * (double)trust[e]
            + 0.2 * (dot / (xn * en) + 1.0)
            + 0.2 * fmax(0.0, 1.0 - (double)stale[e]);
    }
    __syncthreads();

    int kk = kp[0]; kk = kk < 1 ? 1 : (kk > KMAX ? KMAX : kk);

    if (tid < 128) {
        unsigned mask = 0;
        for (int p = 0; p < kk; ++p) {
            double bv = -1e300; int be = 0;
            #pragma unroll
            for (int e = 0; e < 32; ++e) {
                double v = sc[tid * 33 + e];
                if (!((mask >> e) & 1u) && v > bv) { bv = v; be = e; }
            }
            mask |= 1u << be;
            selb[tid * KMAX + p] = (unsigned char)be;
            lposb[tid * KMAX + p] = (unsigned char)atomicAdd(&bcnt[be], 1);
        }
    }
    __syncthreads();
    if (tid < 32) {
        int c = bcnt[tid];
        bbase[tid] = c ? atomicAdd(&counts[tid * CSTRIDE], c) : 0;
    }
    __syncthreads();
    if (tid < 128) {
        int tt = blockIdx.x * 128 + tid;
        for (int p = 0; p < kk; ++p) {
            int e = selb[tid * KMAX + p];
            int pos = bbase[e] + lposb[tid * KMAX + p];
            lists[(size_t)e * B + pos] = tt;
            sel[(size_t)tt * KMAX + p] = (e << 24) | pos;
        }
    }
}

// ---------------------------------------------------------------------------
// K4 v3: grouped expert GEMM (round-10/12 proven — BM=128, BN=128,
// 512 threads = 8 waves, wave tile 32x64, single-buffer 2-barrier K-loop,
// XOR swizzle both sides -> 0 conflicts, bf16 part stores / atomic fallback).
// ---------------------------------------------------------------------------
__global__ __launch_bounds__(512) void k_moe3(
    const ushort* __restrict__ xbf, const ushort* __restrict__ wbf,
    const float* __restrict__ bias, const int* __restrict__ lists,
    const int* __restrict__ counts, const int* __restrict__ offs,
    const int* __restrict__ kp, int B, int C, int D,
    int usePart, ushort* __restrict__ part, float* __restrict__ out)
{
    int e = blockIdx.z;
    int cnt = counts[e * CSTRIDE];
    int row0 = blockIdx.x * 128;
    if (row0 >= cnt) return;            // uniform: safe before barriers
    int col0 = blockIdx.y * 128;
    int nt = min(128, cnt - row0);

    __shared__ ushort xs[128 * 64];     // 16 KB
    __shared__ ushort wsh[128 * 64];    // 16 KB
    __shared__ int toks[128];

    int tid = threadIdx.x;
    if (tid < 128) toks[tid] = (tid < nt) ? lists[(size_t)e * B + row0 + tid] : 0;
    __syncthreads();

    int lane = tid & 63, wid = tid >> 6;
    int wr = wid >> 1, wc = wid & 1;    // wave tile: rows wr*32, cols wc*64
    int l15 = lane & 15, l16 = lane >> 4;

    f32x4 acc[2][4];
    #pragma unroll
    for (int m = 0; m < 2; ++m)
        #pragma unroll
        for (int n = 0; n < 4; ++n) acc[m][n] = (f32x4){0.f, 0.f, 0.f, 0.f};

    int nch = D / 64;
    for (int ch = 0; ch < nch; ++ch) {
        int k0 = ch * 64;
        #pragma unroll
        for (int t = 0; t < 2; ++t) {
            int id = t * 512 + tid;
            int r = id >> 3, seg = id & 7;
            int ssw = (seg ^ (r & 7)) << 3;
            gload_lds16(&xbf[(size_t)toks[r] * D + k0 + ssw],
                        (char*)xs + (size_t)(t * 512 + wid * 64) * 16);
        }
        #pragma unroll
        for (int t = 0; t < 2; ++t) {
            int id = t * 512 + tid;
            int r = id >> 3, seg = id & 7;
            int ssw = (seg ^ (r & 7)) << 3;
            gload_lds16(&wbf[((size_t)e * C + col0 + r) * D + k0 + ssw],
                        (char*)wsh + (size_t)(t * 512 + wid * 64) * 16);
        }
        __syncthreads();
        #pragma unroll
        for (int ks = 0; ks < 2; ++ks) {
            s16x8 a[2], bfr[4];
            int sbase = ks * 4 + l16;
            #pragma unroll
            for (int m = 0; m < 2; ++m) {
                int r = wr * 32 + m * 16 + l15;
                a[m] = *(const s16x8*)&xs[r * 64 + ((sbase ^ (l15 & 7)) << 3)];
            }
            #pragma unroll
            for (int n = 0; n < 4; ++n) {
                int r = wc * 64 + n * 16 + l15;
                bfr[n] = *(const s16x8*)&wsh[r * 64 + ((sbase ^ (l15 & 7)) << 3)];
            }
            #pragma unroll
            for (int m = 0; m < 2; ++m)
                #pragma unroll
                for (int n = 0; n < 4; ++n)
                    acc[m][n] = __builtin_amdgcn_mfma_f32_16x16x32_bf16(
                        a[m], bfr[n], acc[m][n], 0, 0, 0);
        }
        __syncthreads();
    }

    int kk = kp[0]; kk = kk < 1 ? 1 : (kk > KMAX ? KMAX : kk);
    // C/D layout (m89): col = lane&15, row = (lane>>4)*4 + reg
    if (usePart) {
        int slotBase = offs[e] + row0;
        #pragma unroll
        for (int m = 0; m < 2; ++m) {
            int rbase = wr * 32 + m * 16 + l16 * 4;
            #pragma unroll
            for (int n = 0; n < 4; ++n) {
                int col = col0 + wc * 64 + n * 16 + l15;
                float bv = bias[(size_t)e * C + col];
                #pragma unroll
                for (int r = 0; r < 4; ++r) {
                    int rl = rbase + r;
                    if (rl < nt)
                        part[(size_t)(slotBase + rl) * C + col] =
                            f2bf(acc[m][n][r] + bv);
                }
            }
        }
    } else {
        float invk = 1.0f / (float)kk;
        #pragma unroll
        for (int m = 0; m < 2; ++m) {
            int rbase = wr * 32 + m * 16 + l16 * 4;
            #pragma unroll
            for (int n = 0; n < 4; ++n) {
                int col = col0 + wc * 64 + n * 16 + l15;
                float bv = bias[(size_t)e * C + col];
                #pragma unroll
                for (int r = 0; r < 4; ++r) {
                    int rl = rbase + r;
                    if (rl < nt)
                        atomicAdd(&out[(size_t)toks[rl] * C + col],
                                  invk * (acc[m][n][r] + bv));
                }
            }
        }
    }
}

// ---------------------------------------------------------------------------
// K5: combine — out[t][c] = (1/k) * sum_p bf2f(part[slot_p*C + c]).
// ---------------------------------------------------------------------------
__global__ __launch_bounds__(256) void k_combine(
    const ushort* __restrict__ part, const int* __restrict__ sel,
    const int* __restrict__ offs, const int* __restrict__ kp,
    int C, float* __restrict__ out)
{
    int kk = kp[0]; kk = kk < 1 ? 1 : (kk > KMAX ? KMAX : kk);
    float invk = 1.0f / (float)kk;
    int sub = threadIdx.x >> 6, lane = threadIdx.x & 63;
    int t = blockIdx.x * 4 + sub;
    for (int c = lane * 4; c < C; c += 256) {
        float s0 = 0.f, s1 = 0.f, s2 = 0.f, s3 = 0.f;
        for (int p = 0; p < kk; ++p) {
            int sv = sel[(size_t)t * KMAX + p];
            int slot = offs[sv >> 24] + (sv & 0xFFFFFF);
            ushort4 u = *(const ushort4*)&part[(size_t)slot * C + c];
            s0 += bf2f(u.x); s1 += bf2f(u.y); s2 += bf2f(u.z); s3 += bf2f(u.w);
        }
        float4 o = make_float4(invk * s0, invk * s1, invk * s2, invk * s3);
        *(float4*)&out[(size_t)t * C + c] = o;
    }
}

// ===========================================================================
// Legacy fallback — only if ws_size is too small for the bf16 mirrors.
// ===========================================================================
__global__ __launch_bounds__(256) void k_scores_legacy(
    const float* __restrict__ x, const float* __restrict__ ef,
    const float* __restrict__ trust, const float* __restrict__ stale,
    const double* __restrict__ efn, const int* __restrict__ kp,
    int D, int B, int* __restrict__ counts, int* __restrict__ lists)
{
    __shared__ float xs[32][72];
    __shared__ float efs[32][72];
    __shared__ double sc[32][33];

    int tid = threadIdx.x;
    int tl = tid >> 3, eg = tid & 7;
    int tb = blockIdx.x * 32;

    double acc[4] = {0, 0, 0, 0};
    double axx = 0.0;
    int nch = D / 64;

    for (int ch = 0; ch < nch; ++ch) {
        #pragma unroll
        for (int t = 0; t < 2; ++t) {
            int id = t * 256 + tid;
            int r = id >> 4, q = id & 15;
            float4 v = *(const float4*)&x[(size_t)(tb + r) * D + ch * 64 + q * 4];
            *(float4*)&xs[r][q * 4] = v;
            float4 w = *(const float4*)&ef[(size_t)r * D + ch * 64 + q * 4];
            *(float4*)&efs[r][q * 4] = w;
        }
        __syncthreads();
        #pragma unroll 4
        for (int q = 0; q < 16; ++q) {
            float4 xv = *(const float4*)&xs[tl][q * 4];
            double x0 = xv.x, x1 = xv.y, x2 = xv.z, x3 = xv.w;
            axx = fma(x0, x0, fma(x1, x1, fma(x2, x2, fma(x3, x3, axx))));
            #pragma unroll
            for (int j = 0; j < 4; ++j) {
                float4 ev = *(const float4*)&efs[eg + 8 * j][q * 4];
                acc[j] = fma(x0, (double)ev.x, acc[j]);
                acc[j] = fma(x1, (double)ev.y, acc[j]);
                acc[j] = fma(x2, (double)ev.z, acc[j]);
                acc[j] = fma(x3, (double)ev.w, acc[j]);
            }
        }
        __syncthreads();
    }

    double xn = fmax(sqrt(axx), 1e-8);
    #pragma unroll
    for (int j = 0; j < 4; ++j) {
        int e = eg + 8 * j;
        double en = fmax(efn[e], 1e-8);
        double cosv = acc[j] / (xn * en);
        sc[tl][e] = 0.4 * (double)trust[e] + 0.2 * (cosv + 1.0)
                  + 0.2 * fmax(0.0, 1.0 - (double)stale[e]);
    }
    __syncthreads();

    if (tid < 32) {
        int kk = kp[0]; kk = kk < 1 ? 1 : (kk > KMAX ? KMAX : kk);
        unsigned mask = 0;
        int t = tb + tid;
        for (int p = 0; p < kk; ++p) {
            double bv = -1e300; int be = 0;
            #pragma unroll
            for (int e = 0; e < 32; ++e) {
                double v = sc[tid][e];
                if (!((mask >> e) & 1u) && v > bv) { bv = v; be = e; }
            }
            mask |= 1u << be;
            int pos = atomicAdd(&counts[be * CSTRIDE], 1);
            lists[(size_t)be * B + pos] = t;
        }
    }
}

__global__ __launch_bounds__(512) void k_moe_f32(
    const float* __restrict__ x, const float* __restrict__ W,
    const float* __restrict__ bias, const int* __restrict__ lists,
    const int* __restrict__ counts, const int* __restrict__ kp,
    int B, int C, int D, float* __restrict__ out)
{
    int e = blockIdx.z;
    int cnt = counts[e * CSTRIDE];
    int row0 = blockIdx.x * 128;
    if (row0 >= cnt) return;
    int col0 = blockIdx.y * 256;
    int nt = min(128, cnt - row0);

    __shared__ ushort xs[128 * 72];
    __shared__ ushort wsh[256 * 72];
    __shared__ int toks[128];

    int tid = threadIdx.x;
    if (tid < 128) toks[tid] = (tid < nt) ? lists[(size_t)e * B + row0 + tid] : 0;
    __syncthreads();

    int lane = tid & 63, wid = tid >> 6;
    int wr = wid >> 2, wc = wid & 3;
    int l15 = lane & 15, l16 = lane >> 4;

    f32x4 acc[4][4];
    #pragma unroll
    for (int m = 0; m < 4; ++m)
        #pragma unroll
        for (int n = 0; n < 4; ++n) acc[m][n] = (f32x4){0.f, 0.f, 0.f, 0.f};

    int nch = D / 64;
    for (int ch = 0; ch < nch; ++ch) {
        int k0 = ch * 64;
        #pragma unroll
        for (int t = 0; t < 4; ++t) {
            int id = t * 512 + tid;
            int r = id >> 4, q = id & 15;
            float4 v = (r < nt)
                ? *(const float4*)&x[(size_t)toks[r] * D + k0 + q * 4]
                : make_float4(0.f, 0.f, 0.f, 0.f);
            ushort4 u;
            u.x = f2bf(v.x); u.y = f2bf(v.y); u.z = f2bf(v.z); u.w = f2bf(v.w);
            *(ushort4*)&xs[r * 72 + q * 4] = u;
        }
        #pragma unroll
        for (int t = 0; t < 8; ++t) {
            int id = t * 512 + tid;
            int r = id >> 4, q = id & 15;
            float4 v = *(const float4*)&W[((size_t)e * C + col0 + r) * D + k0 + q * 4];
            ushort4 u;
            u.x = f2bf(v.x); u.y = f2bf(v.y); u.z = f2bf(v.z); u.w = f2bf(v.w);
            *(ushort4*)&wsh[r * 72 + q * 4] = u;
        }
        __syncthreads();
        #pragma unroll
        for (int ks = 0; ks < 2; ++ks) {
            s16x8 a[4], bfr[4];
            #pragma unroll
            for (int m = 0; m < 4; ++m)
                a[m] = *(const s16x8*)&xs[(wr * 64 + m * 16 + l15) * 72 + ks * 32 + l16 * 8];
            #pragma unroll
            for (int n = 0; n < 4; ++n)
                bfr[n] = *(const s16x8*)&wsh[(wc * 64 + n * 16 + l15) * 72 + ks * 32 + l16 * 8];
            #pragma unroll
            for (int m = 0; m < 4; ++m)
                #pragma unroll
                for (int n = 0; n < 4; ++n)
                    acc[m][n] = __builtin_amdgcn_mfma_f32_16x16x32_bf16(
                        a[m], bfr[n], acc[m][n], 0, 0, 0);
        }
        __syncthreads();
    }

    int kk = kp[0]; kk = kk < 1 ? 1 : (kk > KMAX ? KMAX : kk);
    float invk = 1.0f / (float)kk;
    #pragma unroll
    for (int m = 0; m < 4; ++m) {
        int rbase = wr * 64 + m * 16 + l16 * 4;
        #pragma unroll
        for (int n = 0; n < 4; ++n) {
            int col = col0 + wc * 64 + n * 16 + l15;
            float bv = bias[(size_t)e * C + col];
            #pragma unroll
            for (int r = 0; r < 4; ++r) {
                int rl = rbase + r;
                if (rl < nt)
                    atomicAdd(&out[(size_t)toks[rl] * C + col],
                              invk * (acc[m][n][r] + bv));
            }
        }
    }
}

// ---------------------------------------------------------------------------
extern "C" void kernel_launch(void* const* d_in, const int* in_sizes, int n_in,
                              void* d_out, int out_size, void* d_ws, size_t ws_size,
                              hipStream_t stream) {
    const float* x     = (const float*)d_in[0];
    const float* ef    = (const float*)d_in[1];
    const float* trust = (const float*)d_in[2];
    const float* stale = (const float*)d_in[3];
    const float* W     = (const float*)d_in[4];
    const float* b     = (const float*)d_in[5];
    const int*   kp    = (const int*)d_in[6];

    int E = in_sizes[2];            // 32
    int D = in_sizes[1] / E;        // 1024
    int B = in_sizes[0] / D;        // 8192
    int C = in_sizes[5] / E;        // 256
    float* out = (float*)d_out;

    // workspace layout
    char* ws = (char*)d_ws;
    double* efn   = (double*)ws;                       // 256 B
    int*    counts= (int*)(ws + 256);                  // 32*CSTRIDE*4 = 8 KB
    size_t off_offs = 256 + 32 * CSTRIDE * 4;
    int*    offs  = (int*)(ws + off_offs);             // 256 B
    size_t off_sel = off_offs + 256;
    int*    sel   = (int*)(ws + off_sel);              // B*KMAX*4
    size_t off_lists = off_sel + (size_t)B * KMAX * 4;
    int*    lists = (int*)(ws + off_lists);            // E*B*4
    size_t off_pacc = off_lists + (size_t)E * B * 4;
    off_pacc = (off_pacc + 255) & ~(size_t)255;
    double* pacc  = (double*)(ws + off_pacc);          // 128*B*8 = 8 MB
    size_t off_paxx = off_pacc + (size_t)128 * B * 8;
    double* paxx  = (double*)(ws + off_paxx);          // 4*B*8
    size_t off_xbf = off_paxx + (size_t)4 * B * 8;
    off_xbf = (off_xbf + 255) & ~(size_t)255;
    ushort* xbf = (ushort*)(ws + off_xbf);             // B*D*2
    size_t off_wbf = off_xbf + (size_t)B * D * 2;
    ushort* wbf = (ushort*)(ws + off_wbf);             // E*C*D*2
    size_t off_part = off_wbf + (size_t)E * C * D * 2;
    off_part = (off_part + 255) & ~(size_t)255;
    ushort* part = (ushort*)(ws + off_part);           // B*KMAX*C*2 bf16 slots
    size_t need_mid  = off_part;
    size_t need_full = off_part + (size_t)B * KMAX * C * 2;

    bool fullPath = ws_size >= need_mid;
    int usePart = (fullPath && ws_size >= need_full) ? 1 : 0;

    if (!usePart)
        hipMemsetAsync(d_out, 0, (size_t)out_size * sizeof(float), stream);

    if (fullPath) {
        int nSB4 = (B / 16) * 4;             // 2048 partial-scores blocks
        k_scores3a<<<nSB4 + E, 256, 0, stream>>>(x, ef, D, B, nSB4, xbf,
                                                 pacc, paxx, efn, counts);
        k_scores3b<<<B / 128, 256, 0, stream>>>(trust, stale, efn, pacc, paxx,
                                                kp, B, counts, lists, sel);
        int perExpF4 = (C * D) / 4;
        dim3 wgrid((perExpF4 + 1023) / 1024, E);
        k_prep_w<<<wgrid, 256, 0, stream>>>(W, counts, perExpF4, wbf, offs);
        dim3 grid((B + 127) / 128, C / 128, E);
        k_moe3<<<grid, 512, 0, stream>>>(xbf, wbf, b, lists, counts, offs, kp,
                                         B, C, D, usePart, part, out);
        if (usePart)
            k_combine<<<B / 4, 256, 0, stream>>>(part, sel, offs, kp, C, out);
    } else {
        k_efnorm<<<E, 64, 0, stream>>>(ef, D, efn, counts);
        k_scores_legacy<<<B / 32, 256, 0, stream>>>(x, ef, trust, stale, efn,
                                                    kp, D, B, counts, lists);
        dim3 grid((B + 127) / 128, C / 256, E);
        k_moe_f32<<<grid, 512, 0, stream>>>(x, W, b, lists, counts, kp,
                                            B, C, D, out);
    }
}